// Round 4
// baseline (1053.578 us; speedup 1.0000x reference)
//
#include <hip/hip_runtime.h>
#include <math.h>

#define PI_F 3.14159265358979323846f

// ---- static config ----
// B=2, HRV=32, WRV=1024, CRV=64; CB=256, HB=200, WB=200
// D=128, COUT=128, HEADS=8, POINTS=6, DH=16
// M = 65536 rows, NV = 40000
//
// Governing arithmetic (MI355X): LDS read = 32 floats/cyc/CU, fp32 FMA =
// 128/cyc/CU -> need >4 FMA per LDS-float to be VALU-bound. 16x8 micro =
// 128 FMA / 24 floats = 5.33.  8x8 = 4.0 (at the roofline; avoid).

__device__ __forceinline__ float gelu_f(float x) {
    return 0.5f * x * (1.0f + erff(x * 0.70710678118654752440f));
}

// ---------------- fused weight prep (+ az table) ----------------
__global__ void prep_weights(const float* __restrict__ pv_w, const float* __restrict__ pv_b,
                             const float* __restrict__ vp_w, const float* __restrict__ vp_b,
                             const float* __restrict__ op_w, const float* __restrict__ op_b,
                             const float* __restrict__ po_w, const float* __restrict__ po_b,
                             const float* __restrict__ pq_w, const float* __restrict__ pq_b,
                             const float* __restrict__ qs_w1, const float* __restrict__ qs_b1,
                             float* __restrict__ pvvp_w, float* __restrict__ pvvp_b,
                             float* __restrict__ oppo_w, float* __restrict__ oppo_b,
                             float* __restrict__ pqqs_w, float* __restrict__ pqqs_b,
                             float2* __restrict__ azsc) {
    int r = blockIdx.x;
    int d = threadIdx.x; // 0..127
    if (r < 256) {
        float s = 0.f;
        for (int k = 0; k < 128; ++k) s += pv_w[r * 128 + k] * vp_w[k * 128 + d];
        pvvp_w[r * 128 + d] = s;
    } else if (r == 256) {
        float s = vp_b[d];
        for (int k = 0; k < 128; ++k) s += pv_b[k] * vp_w[k * 128 + d];
        pvvp_b[d] = s;
    } else if (r < 385) {
        int rr = r - 257;
        float s = 0.f;
        for (int k = 0; k < 128; ++k) s += op_w[rr * 128 + k] * po_w[k * 128 + d];
        oppo_w[rr * 128 + d] = s;
    } else if (r == 385) {
        float s = po_b[d];
        for (int k = 0; k < 128; ++k) s += op_b[k] * po_w[k * 128 + d];
        oppo_b[d] = s;
    } else if (r < 450) {
        int rr = r - 386;
        float s = 0.f;
        for (int k = 0; k < 128; ++k) s += pq_w[rr * 128 + k] * qs_w1[k * 128 + d];
        pqqs_w[rr * 128 + d] = s;
    } else if (r == 450) {
        float s = qs_b1[d];
        for (int k = 0; k < 128; ++k) s += pq_b[k] * qs_w1[k * 128 + d];
        pqqs_b[d] = s;
    } else {
        int w = (r - 451) * 128 + d;
        float az = -PI_F + (float)w * (6.283185307179586f / 1024.0f);
        azsc[w] = make_float2(sinf(az), cosf(az));
    }
}

// ---------------- NT=128 GEMM, 16x8 micro, 128 threads ----------------
// C[M][128] = A[M][lda](cols 0..K-1) @ W[K][128] + bias
// emode 1: += sin(az_m)*ew[0][n] + cos(az_m)*ew[1][n]
// emode 2: += extra2[2m]*ew[0][n] + extra2[2m+1]*ew[1][n]
template <bool STATS>
__global__ __launch_bounds__(128) void gemm_v2(
    const float* __restrict__ A, int lda,
    const float* __restrict__ W,
    const float* __restrict__ bias,
    float* __restrict__ C, int K,
    const float2* __restrict__ azsc,
    const float* __restrict__ extra2,
    const float* __restrict__ extra_w,
    int emode, int do_gelu, float* __restrict__ stats1) {
    __shared__ float As[32][132];
    __shared__ float Ws[32][128];
    __shared__ float sred[8][2];
    const int tid = threadIdx.x;
    const int tn = tid & 15;  // col octet (8 cols)
    const int tm = tid >> 4;  // 0..7: 16-row group
    const int m0 = blockIdx.x * 128;
    if (STATS && tid < 16) sred[tid >> 1][tid & 1] = 0.f;
    float acc[16][8];
#pragma unroll
    for (int i = 0; i < 16; ++i)
#pragma unroll
        for (int j = 0; j < 8; ++j) acc[i][j] = 0.f;

    for (int k0 = 0; k0 < K; k0 += 32) {
        __syncthreads();
        // A tile: 128 rows x 32 k, float4 along k, transpose-scatter to [k][m]
        for (int f = tid; f < 1024; f += 128) {
            int r = f >> 3, c4 = f & 7;
            float4 v = *(const float4*)(A + (size_t)(m0 + r) * lda + k0 + c4 * 4);
            As[c4 * 4 + 0][r] = v.x;
            As[c4 * 4 + 1][r] = v.y;
            As[c4 * 4 + 2][r] = v.z;
            As[c4 * 4 + 3][r] = v.w;
        }
        // W chunk: 32 k x 128 n
        for (int f = tid; f < 1024; f += 128) {
            int kk = f >> 5, n4 = f & 31;
            *(float4*)&Ws[kk][n4 * 4] = *(const float4*)(W + (size_t)(k0 + kk) * 128 + n4 * 4);
        }
        __syncthreads();
#pragma unroll 2
        for (int k = 0; k < 32; ++k) {
            const float4 a0 = *(const float4*)&As[k][tm * 16 + 0];
            const float4 a1 = *(const float4*)&As[k][tm * 16 + 4];
            const float4 a2 = *(const float4*)&As[k][tm * 16 + 8];
            const float4 a3 = *(const float4*)&As[k][tm * 16 + 12];
            const float4 w0 = *(const float4*)&Ws[k][tn * 8];
            const float4 w1 = *(const float4*)&Ws[k][tn * 8 + 4];
            const float av[16] = {a0.x, a0.y, a0.z, a0.w, a1.x, a1.y, a1.z, a1.w,
                                  a2.x, a2.y, a2.z, a2.w, a3.x, a3.y, a3.z, a3.w};
            const float wv[8] = {w0.x, w0.y, w0.z, w0.w, w1.x, w1.y, w1.z, w1.w};
#pragma unroll
            for (int i = 0; i < 16; ++i)
#pragma unroll
                for (int j = 0; j < 8; ++j) acc[i][j] += av[i] * wv[j];
        }
    }
    float bv[8], e0w[8], e1w[8];
#pragma unroll
    for (int j = 0; j < 8; ++j) bv[j] = bias[tn * 8 + j];
    if (emode) {
#pragma unroll
        for (int j = 0; j < 8; ++j) {
            e0w[j] = extra_w[tn * 8 + j];
            e1w[j] = extra_w[128 + tn * 8 + j];
        }
    }
    float ts = 0.f, ts2 = 0.f;
#pragma unroll
    for (int i = 0; i < 16; ++i) {
        int m = m0 + tm * 16 + i;
        float e0 = 0.f, e1 = 0.f;
        if (emode == 1) {
            float2 sc = azsc[m & 1023];
            e0 = sc.x; e1 = sc.y;
        } else if (emode == 2) {
            e0 = extra2[2 * (size_t)m];
            e1 = extra2[2 * (size_t)m + 1];
        }
        float o[8];
#pragma unroll
        for (int j = 0; j < 8; ++j) {
            float v = acc[i][j] + bv[j];
            if (emode) v += e0 * e0w[j] + e1 * e1w[j];
            if (do_gelu) v = gelu_f(v);
            if (STATS) { ts += v; ts2 += v * v; }
            o[j] = v;
        }
        *(float4*)(C + (size_t)m * 128 + tn * 8) = make_float4(o[0], o[1], o[2], o[3]);
        *(float4*)(C + (size_t)m * 128 + tn * 8 + 4) = make_float4(o[4], o[5], o[6], o[7]);
    }
    if (STATS) {
        atomicAdd(&sred[tn >> 1][0], ts);
        atomicAdd(&sred[tn >> 1][1], ts2);
        __syncthreads();
        if (tid < 8) {
            int b = m0 >> 15;
            atomicAdd(&stats1[(b * 8 + tid) * 2 + 0], sred[tid][0]);
            atomicAdd(&stats1[(b * 8 + tid) * 2 + 1], sred[tid][1]);
        }
    }
}

// ---------------- value GEMM (A = bev^T strided), 16x8 micro ----------------
// V[b][n][d] = sum_c bev[b][c][n] * Wf[c][d] + bf[d]; tail-masked at n=40000
__global__ __launch_bounds__(128) void value_gemm(
    const float* __restrict__ bev, const float* __restrict__ Wf,
    const float* __restrict__ bf, float* __restrict__ V) {
    __shared__ float As[32][132];   // [k][n] natural layout (no transpose)
    __shared__ float Ws[32][128];   // [k][d]
    const int tid = threadIdx.x;
    const int tn = tid & 15;  // d octet
    const int tm = tid >> 4;  // 0..7: 16-n group
    const int n0 = blockIdx.x * 128;
    const int b = blockIdx.y;
    const float* bevb = bev + (size_t)b * 256 * 40000;
    float acc[16][8];
#pragma unroll
    for (int i = 0; i < 16; ++i)
#pragma unroll
        for (int j = 0; j < 8; ++j) acc[i][j] = 0.f;

    for (int k0 = 0; k0 < 256; k0 += 32) {
        __syncthreads();
        for (int f = tid; f < 1024; f += 128) {
            int kk = f >> 5, n4 = f & 31;
            int nl = n0 + n4 * 4;
            nl = nl > 39996 ? 39996 : nl;
            *(float4*)&As[kk][n4 * 4] = *(const float4*)(bevb + (size_t)(k0 + kk) * 40000 + nl);
        }
        for (int f = tid; f < 1024; f += 128) {
            int kk = f >> 5, n4 = f & 31;
            *(float4*)&Ws[kk][n4 * 4] = *(const float4*)(Wf + (size_t)(k0 + kk) * 128 + n4 * 4);
        }
        __syncthreads();
#pragma unroll 2
        for (int k = 0; k < 32; ++k) {
            const float4 a0 = *(const float4*)&As[k][tm * 16 + 0];
            const float4 a1 = *(const float4*)&As[k][tm * 16 + 4];
            const float4 a2 = *(const float4*)&As[k][tm * 16 + 8];
            const float4 a3 = *(const float4*)&As[k][tm * 16 + 12];
            const float4 w0 = *(const float4*)&Ws[k][tn * 8];
            const float4 w1 = *(const float4*)&Ws[k][tn * 8 + 4];
            const float av[16] = {a0.x, a0.y, a0.z, a0.w, a1.x, a1.y, a1.z, a1.w,
                                  a2.x, a2.y, a2.z, a2.w, a3.x, a3.y, a3.z, a3.w};
            const float wv[8] = {w0.x, w0.y, w0.z, w0.w, w1.x, w1.y, w1.z, w1.w};
#pragma unroll
            for (int i = 0; i < 16; ++i)
#pragma unroll
                for (int j = 0; j < 8; ++j) acc[i][j] += av[i] * wv[j];
        }
    }
    float bv[8];
#pragma unroll
    for (int j = 0; j < 8; ++j) bv[j] = bf[tn * 8 + j];
#pragma unroll
    for (int i = 0; i < 16; ++i) {
        int n = n0 + tm * 16 + i;
        if (n < 40000) {
            float o[8];
#pragma unroll
            for (int j = 0; j < 8; ++j) o[j] = acc[i][j] + bv[j];
            float* vp = V + ((size_t)b * 40000 + n) * 128 + tn * 8;
            *(float4*)(vp + 0) = make_float4(o[0], o[1], o[2], o[3]);
            *(float4*)(vp + 4) = make_float4(o[4], o[5], o[6], o[7]);
        }
    }
}

// ---------------- small-NT GEMM (8x4 micro) for offs/attw ----------------
template <int MT, int NT, int NTH>
__global__ __launch_bounds__(NTH) void gemm_rn(
    const float* __restrict__ A, int lda,
    const float* __restrict__ W, int ldw,
    const float* __restrict__ bias,
    float* __restrict__ C, int ldc, int K) {
    static_assert(NTH == (MT / 8) * (NT / 4), "thread count mismatch");
    __shared__ float As[32][MT + 4];
    __shared__ float Ws[32][NT];
    constexpr int NTN = NT / 4;
    const int tid = threadIdx.x;
    const int tn = tid % NTN;
    const int tm = tid / NTN;
    const int m0 = blockIdx.x * MT;
    float acc[8][4];
#pragma unroll
    for (int i = 0; i < 8; ++i)
#pragma unroll
        for (int j = 0; j < 4; ++j) acc[i][j] = 0.f;

    for (int k0 = 0; k0 < K; k0 += 32) {
        __syncthreads();
        for (int f = tid; f < MT * 8; f += NTH) {
            int r = f >> 3, c4 = f & 7;
            float4 v = *(const float4*)(A + (size_t)(m0 + r) * lda + k0 + c4 * 4);
            As[c4 * 4 + 0][r] = v.x;
            As[c4 * 4 + 1][r] = v.y;
            As[c4 * 4 + 2][r] = v.z;
            As[c4 * 4 + 3][r] = v.w;
        }
        for (int f = tid; f < 8 * NT; f += NTH) {
            int kk = f / NTN, n4 = f % NTN;
            *(float4*)&Ws[kk][n4 * 4] = *(const float4*)(W + (size_t)(k0 + kk) * ldw + n4 * 4);
        }
        __syncthreads();
#pragma unroll 4
        for (int k = 0; k < 32; ++k) {
            const float4 a0 = *(const float4*)&As[k][tm * 8];
            const float4 a1 = *(const float4*)&As[k][tm * 8 + 4];
            const float4 wv = *(const float4*)&Ws[k][tn * 4];
            acc[0][0] += a0.x * wv.x; acc[0][1] += a0.x * wv.y; acc[0][2] += a0.x * wv.z; acc[0][3] += a0.x * wv.w;
            acc[1][0] += a0.y * wv.x; acc[1][1] += a0.y * wv.y; acc[1][2] += a0.y * wv.z; acc[1][3] += a0.y * wv.w;
            acc[2][0] += a0.z * wv.x; acc[2][1] += a0.z * wv.y; acc[2][2] += a0.z * wv.z; acc[2][3] += a0.z * wv.w;
            acc[3][0] += a0.w * wv.x; acc[3][1] += a0.w * wv.y; acc[3][2] += a0.w * wv.z; acc[3][3] += a0.w * wv.w;
            acc[4][0] += a1.x * wv.x; acc[4][1] += a1.x * wv.y; acc[4][2] += a1.x * wv.z; acc[4][3] += a1.x * wv.w;
            acc[5][0] += a1.y * wv.x; acc[5][1] += a1.y * wv.y; acc[5][2] += a1.y * wv.z; acc[5][3] += a1.y * wv.w;
            acc[6][0] += a1.z * wv.x; acc[6][1] += a1.z * wv.y; acc[6][2] += a1.z * wv.z; acc[6][3] += a1.z * wv.w;
            acc[7][0] += a1.w * wv.x; acc[7][1] += a1.w * wv.y; acc[7][2] += a1.w * wv.z; acc[7][3] += a1.w * wv.w;
        }
    }
#pragma unroll
    for (int i = 0; i < 8; ++i) {
        int m = m0 + tm * 8 + i;
        float4 o;
        o.x = acc[i][0] + bias[tn * 4 + 0];
        o.y = acc[i][1] + bias[tn * 4 + 1];
        o.z = acc[i][2] + bias[tn * 4 + 2];
        o.w = acc[i][3] + bias[tn * 4 + 3];
        *(float4*)(C + (size_t)m * ldc + tn * 4) = o;
    }
}

// ---------------- 3x3 circular conv 128->64, implicit GEMM ----------------
// 128 px x 64 outs per block, 128 thr, micro 8px x 8outs, dx-window reuse:
// per k: 3 A-b128 (12 floats, shared by 3 dx) + 6 W-b128 -> 192 FMA / 36 floats.
// GN1 apply+GELU fused into A staging; GN2 stats fused in epilogue.
__global__ __launch_bounds__(128) void conv3x3_v3(
    const float* __restrict__ H1raw,   // [2][32][1024][128] raw rh1 output
    const float* __restrict__ stats1, const float* __restrict__ g1,
    const float* __restrict__ be1,
    const float* __restrict__ Wc,      // [3][3][128][64]
    float* __restrict__ Y,             // [2][32][1024][64]
    float* __restrict__ stats2) {
    __shared__ float As[32][140];      // [ci][xx], xx 0..129 = x0-1 .. x0+128
    __shared__ float Ws[3][32][64];    // [dx][ci][o]
    __shared__ float ns[128], nb[128];
    const int tid = threadIdx.x;
    const int tn = tid & 7;    // out octet (8 outs)
    const int tm = tid >> 3;   // 0..15: 8-px group
    const int x0 = blockIdx.x * 128;
    const int y = blockIdx.y;
    const int b = blockIdx.z;
    // GN1 normalization coefficients
    {
        int c = tid;
        int g = c >> 4;
        float mean = stats1[(b * 8 + g) * 2 + 0] * (1.0f / 524288.0f);
        float var = stats1[(b * 8 + g) * 2 + 1] * (1.0f / 524288.0f) - mean * mean;
        float rs = 1.0f / sqrtf(var + 1e-5f);
        float sc = rs * g1[c];
        ns[c] = sc;
        nb[c] = be1[c] - mean * sc;
    }
    float acc[8][8];
#pragma unroll
    for (int i = 0; i < 8; ++i)
#pragma unroll
        for (int j = 0; j < 8; ++j) acc[i][j] = 0.f;

    const float* Xb = H1raw + (size_t)b * 32 * 1024 * 128;
    for (int ry = 0; ry < 3; ++ry) {
        const int gy = (y + ry + 31) & 31;
        const float* Xrow = Xb + (size_t)gy * 1024 * 128;
        for (int cc = 0; cc < 128; cc += 32) {
            __syncthreads();
            // A: 130 xx x 8 c4 = 1040 float4, normalized+gelu, transposed [ci][xx]
            for (int f = tid; f < 1040; f += 128) {
                int xx = f >> 3, c4 = f & 7;
                int gx = (x0 + xx + 1023) & 1023;
                float4 v = *(const float4*)(Xrow + (size_t)gx * 128 + cc + c4 * 4);
                int c = cc + c4 * 4;
                As[c4 * 4 + 0][xx] = gelu_f(v.x * ns[c + 0] + nb[c + 0]);
                As[c4 * 4 + 1][xx] = gelu_f(v.y * ns[c + 1] + nb[c + 1]);
                As[c4 * 4 + 2][xx] = gelu_f(v.z * ns[c + 2] + nb[c + 2]);
                As[c4 * 4 + 3][xx] = gelu_f(v.w * ns[c + 3] + nb[c + 3]);
            }
            // W: 3 dx x 32 ci x 16 o4 = 1536 float4
            for (int f = tid; f < 1536; f += 128) {
                int o4 = f & 15;
                int ci = (f >> 4) & 31;
                int dx = f >> 9;
                *(float4*)&Ws[dx][ci][o4 * 4] =
                    *(const float4*)(Wc + ((size_t)(ry * 3 + dx) * 128 + cc + ci) * 64 + o4 * 4);
            }
            __syncthreads();
#pragma unroll 2
            for (int k = 0; k < 32; ++k) {
                const float4 a0 = *(const float4*)&As[k][tm * 8 + 0];
                const float4 a1 = *(const float4*)&As[k][tm * 8 + 4];
                const float4 a2 = *(const float4*)&As[k][tm * 8 + 8];
                const float r[12] = {a0.x, a0.y, a0.z, a0.w, a1.x, a1.y, a1.z, a1.w,
                                     a2.x, a2.y, a2.z, a2.w};
#pragma unroll
                for (int dx = 0; dx < 3; ++dx) {
                    const float4 w0 = *(const float4*)&Ws[dx][k][tn * 8];
                    const float4 w1 = *(const float4*)&Ws[dx][k][tn * 8 + 4];
                    const float wv[8] = {w0.x, w0.y, w0.z, w0.w, w1.x, w1.y, w1.z, w1.w};
#pragma unroll
                    for (int i = 0; i < 8; ++i)
#pragma unroll
                        for (int j = 0; j < 8; ++j) acc[i][j] += r[i + dx] * wv[j];
                }
            }
        }
    }
    // GN2 stats: thread's 8 outs = exactly group g = tn (CPG=8)
    float s = 0.f, q = 0.f;
#pragma unroll
    for (int i = 0; i < 8; ++i)
#pragma unroll
        for (int j = 0; j < 8; ++j) { s += acc[i][j]; q += acc[i][j] * acc[i][j]; }
#pragma unroll
    for (int mk = 8; mk < 64; mk <<= 1) {
        s += __shfl_xor(s, mk);
        q += __shfl_xor(q, mk);
    }
    if ((tid & 63) < 8) {
        atomicAdd(&stats2[(b * 8 + tn) * 2 + 0], s);
        atomicAdd(&stats2[(b * 8 + tn) * 2 + 1], q);
    }
#pragma unroll
    for (int i = 0; i < 8; ++i) {
        int x = x0 + tm * 8 + i;
        float* yp = Y + (((size_t)(b * 32 + y) * 1024 + x) * 64 + tn * 8);
        *(float4*)(yp + 0) = make_float4(acc[i][0], acc[i][1], acc[i][2], acc[i][3]);
        *(float4*)(yp + 4) = make_float4(acc[i][4], acc[i][5], acc[i][6], acc[i][7]);
    }
}

// ---------------- fused GN2-apply + GELU + rh3 head ----------------
__global__ __launch_bounds__(256) void rh3_kernel(
    const float* __restrict__ H2,  // [65536][64] UN-normalized conv output
    const float* __restrict__ stats, const float* __restrict__ gamma,
    const float* __restrict__ beta, float inv_cnt,
    const float* __restrict__ w3, const float* __restrict__ b3,
    const float2* __restrict__ azsc,
    float2* __restrict__ refxy, float2* __restrict__ sigf) {
    const int tid = threadIdx.x;
    const int lane = tid & 15;
    const int m = blockIdx.x * 16 + (tid >> 4);
    const int b = m >> 15;
    const int c = lane * 4;
    const int g = c >> 3;  // CPG=8
    float mean = stats[(b * 8 + g) * 2 + 0] * inv_cnt;
    float var = stats[(b * 8 + g) * 2 + 1] * inv_cnt - mean * mean;
    float rs = 1.0f / sqrtf(var + 1e-5f);
    float4 v = *(const float4*)(H2 + (size_t)m * 64 + c);
    float hv[4];
    hv[0] = gelu_f((v.x - mean) * rs * gamma[c + 0] + beta[c + 0]);
    hv[1] = gelu_f((v.y - mean) * rs * gamma[c + 1] + beta[c + 1]);
    hv[2] = gelu_f((v.z - mean) * rs * gamma[c + 2] + beta[c + 2]);
    hv[3] = gelu_f((v.w - mean) * rs * gamma[c + 3] + beta[c + 3]);
    float d0 = 0.f, d1 = 0.f;
#pragma unroll
    for (int k = 0; k < 4; ++k) {
        d0 += hv[k] * w3[(c + k) * 2 + 0];
        d1 += hv[k] * w3[(c + k) * 2 + 1];
    }
#pragma unroll
    for (int s = 1; s < 16; s <<= 1) {
        d0 += __shfl_xor(d0, s, 16);
        d1 += __shfl_xor(d1, s, 16);
    }
    if (lane == 0) {
        float mu = fminf(fmaxf(d0 + b3[0], 0.f), 55.f);
        float ls = fminf(fmaxf(d1 + b3[1], -5.f), 3.f);
        float sg = expf(ls);
        float2 sc = azsc[m & 1023];
        float x_mu = mu * sc.y;
        float y_mu = mu * sc.x;
        float rx = fminf(fmaxf(x_mu * 0.01f + 0.5f, 0.f), 1.f);
        float ry = fminf(fmaxf(y_mu * 0.01f + 0.5f, 0.f), 1.f);
        refxy[m] = make_float2(rx, ry);
        sigf[m] = make_float2(ls, 1.f / (sg + 1e-6f));
    }
}

// ---------------- MSDA bilinear sampling ----------------
__device__ __forceinline__ float samp_v(const float* __restrict__ Vb, int x, int y) {
    bool valid = ((unsigned)x < 200u) && ((unsigned)y < 200u);
    int xc = min(max(x, 0), 199);
    int yc = min(max(y, 0), 199);
    float v = Vb[((size_t)yc * 200 + xc) * 128];
    return valid ? v : 0.f;
}

__global__ __launch_bounds__(256) void msda_kernel(
    const float* __restrict__ V,       // [2][40000][128]
    const float2* __restrict__ refxy,  // [65536]
    const float* __restrict__ offs,    // [65536][96]
    const float* __restrict__ aw,      // [65536][48]
    float* __restrict__ out) {         // [65536][128]
    const int tid = threadIdx.x;
    const int lane = tid & 15;
    const int grp = tid >> 4;
    const int m = blockIdx.x * 2 + (grp >> 3);
    const int head = grp & 7;
    const int b = m >> 15;
    float2 r = refxy[m];
    const float* lg = aw + (size_t)m * 48 + head * 6;
    float l[6];
#pragma unroll
    for (int p = 0; p < 6; ++p) l[p] = lg[p];
    float mx = l[0];
#pragma unroll
    for (int p = 1; p < 6; ++p) mx = fmaxf(mx, l[p]);
    float s = 0.f;
#pragma unroll
    for (int p = 0; p < 6; ++p) { l[p] = expf(l[p] - mx); s += l[p]; }
    float inv = 1.f / s;
    const float* of = offs + (size_t)m * 96 + head * 12;
    const float* Vb = V + (size_t)b * 40000 * 128 + head * 16 + lane;
    float acc = 0.f;
#pragma unroll
    for (int p = 0; p < 6; ++p) {
        float px = r.x * 200.f + of[p * 2 + 0] - 0.5f;
        float py = r.y * 200.f + of[p * 2 + 1] - 0.5f;
        float fx = floorf(px), fy = floorf(py);
        int x0 = (int)fx, y0 = (int)fy;
        float wx = px - fx, wy = py - fy;
        float v00 = samp_v(Vb, x0, y0);
        float v10 = samp_v(Vb, x0 + 1, y0);
        float v01 = samp_v(Vb, x0, y0 + 1);
        float v11 = samp_v(Vb, x0 + 1, y0 + 1);
        float bil = v00 * (1.f - wx) * (1.f - wy) + v10 * wx * (1.f - wy) +
                    v01 * (1.f - wx) * wy + v11 * wx * wy;
        acc += l[p] * inv * bil;
    }
    out[(size_t)m * 128 + head * 16 + lane] = acc;
}

// ---------------- launch ----------------
extern "C" void kernel_launch(void* const* d_in, const int* in_sizes, int n_in,
                              void* d_out, int out_size, void* d_ws, size_t ws_size,
                              hipStream_t stream) {
    const float* x_rv = (const float*)d_in[0];
    const float* bev = (const float*)d_in[1];
    const float* pq_w = (const float*)d_in[2];
    const float* pq_b = (const float*)d_in[3];
    const float* pv_w = (const float*)d_in[4];
    const float* pv_b = (const float*)d_in[5];
    const float* po_w = (const float*)d_in[6];
    const float* po_b = (const float*)d_in[7];
    const float* qs_w1 = (const float*)d_in[8];
    const float* qs_b1 = (const float*)d_in[9];
    const float* qs_w2 = (const float*)d_in[10];
    const float* qs_b2 = (const float*)d_in[11];
    const float* rh_w1 = (const float*)d_in[12];
    const float* rh_b1 = (const float*)d_in[13];
    const float* rh_g1 = (const float*)d_in[14];
    const float* rh_be1 = (const float*)d_in[15];
    const float* rh_w2 = (const float*)d_in[16];
    const float* rh_g2 = (const float*)d_in[17];
    const float* rh_be2 = (const float*)d_in[18];
    const float* rh_w3 = (const float*)d_in[19];
    const float* rh_b3 = (const float*)d_in[20];
    const float* so_w = (const float*)d_in[21];
    const float* so_b = (const float*)d_in[22];
    const float* aw_w = (const float*)d_in[23];
    const float* aw_b = (const float*)d_in[24];
    const float* vp_w = (const float*)d_in[25];
    const float* vp_b = (const float*)d_in[26];
    const float* op_w = (const float*)d_in[27];
    const float* op_b = (const float*)d_in[28];

    const int M = 65536;

    float* ws = (float*)d_ws;
    float* azsc = ws;    ws += 2048;
    float* pvvp_w = ws;  ws += 256 * 128;
    float* pvvp_b = ws;  ws += 128;
    float* oppo_w = ws;  ws += 128 * 128;
    float* oppo_b = ws;  ws += 128;
    float* pqqs_w = ws;  ws += 64 * 128;
    float* pqqs_b = ws;  ws += 128;
    float* stats = ws;   ws += 64;   // [0:32) GN1, [32:64) GN2
    float* Vv = ws;      ws += (size_t)80000 * 128;
    float* h1 = ws;      ws += (size_t)M * 128;
    float* h2 = ws;      ws += (size_t)M * 64;
    float* q1 = ws;      ws += (size_t)M * 128;
    float* refxy = ws;   ws += (size_t)M * 2;
    float* sigf = ws;    ws += (size_t)M * 2;
    size_t need_bytes = (size_t)(ws - (float*)d_ws) * sizeof(float);
    if (ws_size < need_bytes) return;
    float* query = h1;  // h1 (raw rh1) dead after conv
    float* offs = q1;   // q1 dead after qs2
    float* attw = h2;   // h2 dead after rh3
    float* mo = h1;     // query dead after offs/attw

    float2* azsc2 = (float2*)azsc;
    float2* refxy2 = (float2*)refxy;
    float2* sigf2 = (float2*)sigf;

    prep_weights<<<459, 128, 0, stream>>>(pv_w, pv_b, vp_w, vp_b, op_w, op_b, po_w, po_b,
                                          pq_w, pq_b, qs_w1, qs_b1,
                                          pvvp_w, pvvp_b, oppo_w, oppo_b, pqqs_w, pqqs_b, azsc2);
    hipMemsetAsync(stats, 0, 64 * sizeof(float), stream);

    // h1 = raw (concat(x_rv,[sin,cos,0]) @ rh_w1 + rh_b1); fused GN1 stats
    gemm_v2<true><<<M / 128, 128, 0, stream>>>(
        x_rv, 64, rh_w1, rh_b1, h1, 64, azsc2, nullptr, rh_w1 + 64 * 128, 1, 0, stats);

    // value = bev^T @ (pv_w@vp_w) + fused bias
    value_gemm<<<dim3(313, 2), 128, 0, stream>>>(bev, pvvp_w, pvvp_b, Vv);

    // conv: GN1-apply+gelu fused in staging; GN2 stats fused in epilogue
    conv3x3_v3<<<dim3(8, 32, 2), 128, 0, stream>>>(h1, stats, rh_g1, rh_be1,
                                                   rh_w2, h2, stats + 32);

    // fused GN2-apply + gelu + rh3 head
    rh3_kernel<<<4096, 256, 0, stream>>>(h2, stats + 32, rh_g2, rh_be2, 1.0f / 262144.0f,
                                         rh_w3, rh_b3, azsc2, refxy2, sigf2);

    // q1 = gelu(x_rv @ (pq_w@qs_w1a) + sigf extras + fused bias)
    gemm_v2<false><<<M / 128, 128, 0, stream>>>(
        x_rv, 64, pqqs_w, pqqs_b, q1, 64, nullptr, sigf, qs_w1 + 128 * 128, 2, 1, nullptr);

    // query = q1 @ qs_w2 + qs_b2  (into h1)
    gemm_v2<false><<<M / 128, 128, 0, stream>>>(
        q1, 128, qs_w2, qs_b2, query, 128, nullptr, nullptr, nullptr, 0, 0, nullptr);

    // offs = query @ so_w + so_b  (into q1)
    gemm_rn<64, 96, 192><<<M / 64, 192, 0, stream>>>(
        query, 128, so_w, 96, so_b, offs, 96, 128);

    // attw logits = query @ aw_w + aw_b  (into h2)
    gemm_rn<128, 48, 192><<<M / 128, 192, 0, stream>>>(
        query, 128, aw_w, 48, aw_b, attw, 48, 128);

    // MSDA sampling (into h1; query dead)
    msda_kernel<<<M / 2, 256, 0, stream>>>(Vv, refxy2, offs, attw, mo);

    // y = mo @ (op_w@po_w) + fused bias -> d_out
    gemm_v2<false><<<M / 128, 128, 0, stream>>>(
        mo, 128, oppo_w, oppo_b, (float*)d_out, 128, nullptr, nullptr, nullptr, 0, 0, nullptr);
}

// Round 5
// 654.609 us; speedup vs baseline: 1.6095x; 1.6095x over previous
//
#include <hip/hip_runtime.h>
#include <math.h>

#define PI_F 3.14159265358979323846f

// ---- static config ----
// B=2, HRV=32, WRV=1024, CRV=64; CB=256, HB=200, WB=200
// D=128, COUT=128, HEADS=8, POINTS=6, DH=16; M=65536, NV=40000
//
// Hard-won rules (rounds 1-4):
//  - >=8-16 waves/CU or latency kills you (grid/256 * waves_per_block).
//  - FMA per LDS-float >= 4 (LDS 32 fl/cyc vs 128 FMA/cyc per CU).
//  - LDS leading dim: 12 (mod 32) and 0 (mod 4) -> conflict-free scatter + b128.

__device__ __forceinline__ float gelu_f(float x) {
    return 0.5f * x * (1.0f + erff(x * 0.70710678118654752440f));
}

// ---------------- fused weight prep (+ az table) ----------------
// pvvp = pv_w@vp_w (+bias fold); oppo = op_w@po_w; pqqs = pq_w@qs_w1
// qsso = qs_w2@so_w; qsaw = qs_w2@aw_w  (query GEMM eliminated: linear chain)
__global__ void prep_weights(const float* __restrict__ pv_w, const float* __restrict__ pv_b,
                             const float* __restrict__ vp_w, const float* __restrict__ vp_b,
                             const float* __restrict__ op_w, const float* __restrict__ op_b,
                             const float* __restrict__ po_w, const float* __restrict__ po_b,
                             const float* __restrict__ pq_w, const float* __restrict__ pq_b,
                             const float* __restrict__ qs_w1, const float* __restrict__ qs_b1,
                             const float* __restrict__ qs_w2, const float* __restrict__ qs_b2,
                             const float* __restrict__ so_w, const float* __restrict__ so_b,
                             const float* __restrict__ aw_w, const float* __restrict__ aw_b,
                             float* __restrict__ pvvp_w, float* __restrict__ pvvp_b,
                             float* __restrict__ oppo_w, float* __restrict__ oppo_b,
                             float* __restrict__ pqqs_w, float* __restrict__ pqqs_b,
                             float* __restrict__ qsso_w, float* __restrict__ qsso_b,
                             float* __restrict__ qsaw_w, float* __restrict__ qsaw_b,
                             float2* __restrict__ azsc) {
    int r = blockIdx.x;
    int d = threadIdx.x; // 0..127
    if (r < 256) {
        float s = 0.f;
        for (int k = 0; k < 128; ++k) s += pv_w[r * 128 + k] * vp_w[k * 128 + d];
        pvvp_w[r * 128 + d] = s;
    } else if (r == 256) {
        float s = vp_b[d];
        for (int k = 0; k < 128; ++k) s += pv_b[k] * vp_w[k * 128 + d];
        pvvp_b[d] = s;
    } else if (r < 385) {
        int rr = r - 257;
        float s = 0.f;
        for (int k = 0; k < 128; ++k) s += op_w[rr * 128 + k] * po_w[k * 128 + d];
        oppo_w[rr * 128 + d] = s;
    } else if (r == 385) {
        float s = po_b[d];
        for (int k = 0; k < 128; ++k) s += op_b[k] * po_w[k * 128 + d];
        oppo_b[d] = s;
    } else if (r < 450) {
        int rr = r - 386;
        float s = 0.f;
        for (int k = 0; k < 128; ++k) s += pq_w[rr * 128 + k] * qs_w1[k * 128 + d];
        pqqs_w[rr * 128 + d] = s;
    } else if (r == 450) {
        float s = qs_b1[d];
        for (int k = 0; k < 128; ++k) s += pq_b[k] * qs_w1[k * 128 + d];
        pqqs_b[d] = s;
    } else if (r < 459) {
        int w = (r - 451) * 128 + d;
        float az = -PI_F + (float)w * (6.283185307179586f / 1024.0f);
        azsc[w] = make_float2(sinf(az), cosf(az));
    } else if (r < 587) {
        int rr = r - 459;
        if (d < 96) {
            float s = 0.f;
            for (int k = 0; k < 128; ++k) s += qs_w2[rr * 128 + k] * so_w[k * 96 + d];
            qsso_w[rr * 96 + d] = s;
        }
    } else if (r == 587) {
        if (d < 96) {
            float s = so_b[d];
            for (int k = 0; k < 128; ++k) s += qs_b2[k] * so_w[k * 96 + d];
            qsso_b[d] = s;
        }
    } else if (r < 716) {
        int rr = r - 588;
        if (d < 48) {
            float s = 0.f;
            for (int k = 0; k < 128; ++k) s += qs_w2[rr * 128 + k] * aw_w[k * 48 + d];
            qsaw_w[rr * 48 + d] = s;
        }
    } else {
        if (d < 48) {
            float s = aw_b[d];
            for (int k = 0; k < 128; ++k) s += qs_b2[k] * aw_w[k * 48 + d];
            qsaw_b[d] = s;
        }
    }
}

// ---------------- MT=128 GEMM, 8x8 micro, 2*NT threads ----------------
// C[M][NT] = A[M][lda](cols 0..K-1) @ W[K][NT] + bias ; grid = M/128
// emode 1: += sin(az)*ew[0][n] + cos(az)*ew[1][n]; emode 2: extra2 pairs
template <int NT, bool STATS>
__global__ __launch_bounds__(2 * NT) void gemm_v3(
    const float* __restrict__ A, int lda,
    const float* __restrict__ W,
    const float* __restrict__ bias,
    float* __restrict__ C, int K,
    const float2* __restrict__ azsc,
    const float* __restrict__ extra2,
    const float* __restrict__ extra_w,
    int emode, int do_gelu, float* __restrict__ stats1) {
    constexpr int NTH = 2 * NT;
    constexpr int NTO = NT / 8;
    __shared__ float As[32][140];   // 140 % 32 = 12 -> conflict-free scatter
    __shared__ float Ws[32][NT];
    __shared__ float sred[8][2];
    const int tid = threadIdx.x;
    const int tn = tid % NTO;
    const int tm = tid / NTO;   // 0..15
    const int m0 = blockIdx.x * 128;
    if (STATS && tid < 16) sred[tid >> 1][tid & 1] = 0.f;
    float acc[8][8];
#pragma unroll
    for (int i = 0; i < 8; ++i)
#pragma unroll
        for (int j = 0; j < 8; ++j) acc[i][j] = 0.f;

    for (int k0 = 0; k0 < K; k0 += 32) {
        __syncthreads();
        for (int f = tid; f < 1024; f += NTH) {
            int r = f >> 3, c4 = f & 7;
            float4 v = *(const float4*)(A + (size_t)(m0 + r) * lda + k0 + c4 * 4);
            As[c4 * 4 + 0][r] = v.x;
            As[c4 * 4 + 1][r] = v.y;
            As[c4 * 4 + 2][r] = v.z;
            As[c4 * 4 + 3][r] = v.w;
        }
        for (int f = tid; f < 8 * NT; f += NTH) {
            int kk = f / (NT / 4), n4 = f % (NT / 4);
            *(float4*)&Ws[kk][n4 * 4] = *(const float4*)(W + (size_t)(k0 + kk) * NT + n4 * 4);
        }
        __syncthreads();
#pragma unroll 2
        for (int k = 0; k < 32; ++k) {
            const float4 a0 = *(const float4*)&As[k][tm * 8];
            const float4 a1 = *(const float4*)&As[k][tm * 8 + 4];
            const float4 w0 = *(const float4*)&Ws[k][tn * 8];
            const float4 w1 = *(const float4*)&Ws[k][tn * 8 + 4];
            const float av[8] = {a0.x, a0.y, a0.z, a0.w, a1.x, a1.y, a1.z, a1.w};
            const float wv[8] = {w0.x, w0.y, w0.z, w0.w, w1.x, w1.y, w1.z, w1.w};
#pragma unroll
            for (int i = 0; i < 8; ++i)
#pragma unroll
                for (int j = 0; j < 8; ++j) acc[i][j] += av[i] * wv[j];
        }
    }
    float bv[8], e0w[8], e1w[8];
#pragma unroll
    for (int j = 0; j < 8; ++j) bv[j] = bias[tn * 8 + j];
    if (emode) {
#pragma unroll
        for (int j = 0; j < 8; ++j) {
            e0w[j] = extra_w[tn * 8 + j];
            e1w[j] = extra_w[NT + tn * 8 + j];
        }
    }
    float ts = 0.f, ts2 = 0.f;
#pragma unroll
    for (int i = 0; i < 8; ++i) {
        int m = m0 + tm * 8 + i;
        float e0 = 0.f, e1 = 0.f;
        if (emode == 1) {
            float2 sc = azsc[m & 1023];
            e0 = sc.x; e1 = sc.y;
        } else if (emode == 2) {
            e0 = extra2[2 * (size_t)m];
            e1 = extra2[2 * (size_t)m + 1];
        }
        float o[8];
#pragma unroll
        for (int j = 0; j < 8; ++j) {
            float v = acc[i][j] + bv[j];
            if (emode) v += e0 * e0w[j] + e1 * e1w[j];
            if (do_gelu) v = gelu_f(v);
            if (STATS) { ts += v; ts2 += v * v; }
            o[j] = v;
        }
        *(float4*)(C + (size_t)m * NT + tn * 8) = make_float4(o[0], o[1], o[2], o[3]);
        *(float4*)(C + (size_t)m * NT + tn * 8 + 4) = make_float4(o[4], o[5], o[6], o[7]);
    }
    if (STATS) {  // C=128, CPG=16: thread's 8 cols lie in group tn>>1
        atomicAdd(&sred[tn >> 1][0], ts);
        atomicAdd(&sred[tn >> 1][1], ts2);
        __syncthreads();
        if (tid < 8) {
            int b = m0 >> 15;
            atomicAdd(&stats1[(b * 8 + tid) * 2 + 0], sred[tid][0]);
            atomicAdd(&stats1[(b * 8 + tid) * 2 + 1], sred[tid][1]);
        }
    }
}

// ---------------- small-NT GEMM (8x4 micro) for attw ----------------
template <int MT, int NT, int NTH>
__global__ __launch_bounds__(NTH) void gemm_rn(
    const float* __restrict__ A, int lda,
    const float* __restrict__ W, int ldw,
    const float* __restrict__ bias,
    float* __restrict__ C, int ldc, int K) {
    static_assert(NTH == (MT / 8) * (NT / 4), "thread count mismatch");
    __shared__ float As[32][MT + 12];
    __shared__ float Ws[32][NT];
    constexpr int NTN = NT / 4;
    const int tid = threadIdx.x;
    const int tn = tid % NTN;
    const int tm = tid / NTN;
    const int m0 = blockIdx.x * MT;
    float acc[8][4];
#pragma unroll
    for (int i = 0; i < 8; ++i)
#pragma unroll
        for (int j = 0; j < 4; ++j) acc[i][j] = 0.f;

    for (int k0 = 0; k0 < K; k0 += 32) {
        __syncthreads();
        for (int f = tid; f < MT * 8; f += NTH) {
            int r = f >> 3, c4 = f & 7;
            float4 v = *(const float4*)(A + (size_t)(m0 + r) * lda + k0 + c4 * 4);
            As[c4 * 4 + 0][r] = v.x;
            As[c4 * 4 + 1][r] = v.y;
            As[c4 * 4 + 2][r] = v.z;
            As[c4 * 4 + 3][r] = v.w;
        }
        for (int f = tid; f < 8 * NT; f += NTH) {
            int kk = f / NTN, n4 = f % NTN;
            *(float4*)&Ws[kk][n4 * 4] = *(const float4*)(W + (size_t)(k0 + kk) * ldw + n4 * 4);
        }
        __syncthreads();
#pragma unroll 4
        for (int k = 0; k < 32; ++k) {
            const float4 a0 = *(const float4*)&As[k][tm * 8];
            const float4 a1 = *(const float4*)&As[k][tm * 8 + 4];
            const float4 wv = *(const float4*)&Ws[k][tn * 4];
            acc[0][0] += a0.x * wv.x; acc[0][1] += a0.x * wv.y; acc[0][2] += a0.x * wv.z; acc[0][3] += a0.x * wv.w;
            acc[1][0] += a0.y * wv.x; acc[1][1] += a0.y * wv.y; acc[1][2] += a0.y * wv.z; acc[1][3] += a0.y * wv.w;
            acc[2][0] += a0.z * wv.x; acc[2][1] += a0.z * wv.y; acc[2][2] += a0.z * wv.z; acc[2][3] += a0.z * wv.w;
            acc[3][0] += a0.w * wv.x; acc[3][1] += a0.w * wv.y; acc[3][2] += a0.w * wv.z; acc[3][3] += a0.w * wv.w;
            acc[4][0] += a1.x * wv.x; acc[4][1] += a1.x * wv.y; acc[4][2] += a1.x * wv.z; acc[4][3] += a1.x * wv.w;
            acc[5][0] += a1.y * wv.x; acc[5][1] += a1.y * wv.y; acc[5][2] += a1.y * wv.z; acc[5][3] += a1.y * wv.w;
            acc[6][0] += a1.z * wv.x; acc[6][1] += a1.z * wv.y; acc[6][2] += a1.z * wv.z; acc[6][3] += a1.z * wv.w;
            acc[7][0] += a1.w * wv.x; acc[7][1] += a1.w * wv.y; acc[7][2] += a1.w * wv.z; acc[7][3] += a1.w * wv.w;
        }
    }
#pragma unroll
    for (int i = 0; i < 8; ++i) {
        int m = m0 + tm * 8 + i;
        float4 o;
        o.x = acc[i][0] + bias[tn * 4 + 0];
        o.y = acc[i][1] + bias[tn * 4 + 1];
        o.z = acc[i][2] + bias[tn * 4 + 2];
        o.w = acc[i][3] + bias[tn * 4 + 3];
        *(float4*)(C + (size_t)m * ldc + tn * 4) = o;
    }
}

// ---------------- value GEMM (A = bev^T strided), 256 thr ----------------
__global__ __launch_bounds__(256) void value_gemm(
    const float* __restrict__ bev, const float* __restrict__ Wf,
    const float* __restrict__ bf, float* __restrict__ V) {
    __shared__ float As[32][140];   // [k][n] natural layout
    __shared__ float Ws[32][128];   // [k][d]
    const int tid = threadIdx.x;
    const int tn = tid & 15;
    const int tm = tid >> 4;  // 0..15
    const int n0 = blockIdx.x * 128;
    const int b = blockIdx.y;
    const float* bevb = bev + (size_t)b * 256 * 40000;
    float acc[8][8];
#pragma unroll
    for (int i = 0; i < 8; ++i)
#pragma unroll
        for (int j = 0; j < 8; ++j) acc[i][j] = 0.f;

    for (int k0 = 0; k0 < 256; k0 += 32) {
        __syncthreads();
        for (int f = tid; f < 1024; f += 256) {
            int kk = f >> 5, n4 = f & 31;
            int nl = n0 + n4 * 4;
            nl = nl > 39996 ? 39996 : nl;
            *(float4*)&As[kk][n4 * 4] = *(const float4*)(bevb + (size_t)(k0 + kk) * 40000 + nl);
        }
        for (int f = tid; f < 1024; f += 256) {
            int kk = f >> 5, n4 = f & 31;
            *(float4*)&Ws[kk][n4 * 4] = *(const float4*)(Wf + (size_t)(k0 + kk) * 128 + n4 * 4);
        }
        __syncthreads();
#pragma unroll 2
        for (int k = 0; k < 32; ++k) {
            const float4 a0 = *(const float4*)&As[k][tm * 8];
            const float4 a1 = *(const float4*)&As[k][tm * 8 + 4];
            const float4 w0 = *(const float4*)&Ws[k][tn * 8];
            const float4 w1 = *(const float4*)&Ws[k][tn * 8 + 4];
            const float av[8] = {a0.x, a0.y, a0.z, a0.w, a1.x, a1.y, a1.z, a1.w};
            const float wv[8] = {w0.x, w0.y, w0.z, w0.w, w1.x, w1.y, w1.z, w1.w};
#pragma unroll
            for (int i = 0; i < 8; ++i)
#pragma unroll
                for (int j = 0; j < 8; ++j) acc[i][j] += av[i] * wv[j];
        }
    }
    float bv[8];
#pragma unroll
    for (int j = 0; j < 8; ++j) bv[j] = bf[tn * 8 + j];
#pragma unroll
    for (int i = 0; i < 8; ++i) {
        int n = n0 + tm * 8 + i;
        if (n < 40000) {
            float o[8];
#pragma unroll
            for (int j = 0; j < 8; ++j) o[j] = acc[i][j] + bv[j];
            float* vp = V + ((size_t)b * 40000 + n) * 128 + tn * 8;
            *(float4*)(vp + 0) = make_float4(o[0], o[1], o[2], o[3]);
            *(float4*)(vp + 4) = make_float4(o[4], o[5], o[6], o[7]);
        }
    }
}

// ---------------- 3x3 circular conv 128->64, k-split-4 ----------------
// 64px x 64out tiles, 256 thr = 8 pg x 8 og x 4 ksplit, grid 1024 ->
// 4 blocks/CU x 4 waves = 16 waves/CU. micro 8px x 8out, dx-window reuse
// (192 FMA / 36 LDS-floats). GN1-apply+gelu in staging; GN2 stats epilogue.
__global__ __launch_bounds__(256, 4) void conv3x3_v4(
    const float* __restrict__ H1raw, const float* __restrict__ stats1,
    const float* __restrict__ g1, const float* __restrict__ be1,
    const float* __restrict__ Wc, float* __restrict__ Y,
    float* __restrict__ stats2) {
    __shared__ float As[32][76];     // [ci][xx], xx 0..65 ; 76 % 32 = 12
    __shared__ float Ws[3][32][64];  // [dx][ci][o] ; reused as reduce buf
    __shared__ float ns[128], nb[128];
    const int tid = threadIdx.x;
    const int og = tid & 7;
    const int pg = (tid >> 3) & 7;
    const int ks = tid >> 6;  // k-split 0..3
    const int x0 = blockIdx.x * 64;
    const int y = blockIdx.y;
    const int b = blockIdx.z;
    if (tid < 128) {
        int c = tid, g = c >> 4;
        float mean = stats1[(b * 8 + g) * 2 + 0] * (1.0f / 524288.0f);
        float var = stats1[(b * 8 + g) * 2 + 1] * (1.0f / 524288.0f) - mean * mean;
        float rs = 1.0f / sqrtf(var + 1e-5f);
        float sc = rs * g1[c];
        ns[c] = sc;
        nb[c] = be1[c] - mean * sc;
    }
    float acc[8][8];
#pragma unroll
    for (int i = 0; i < 8; ++i)
#pragma unroll
        for (int j = 0; j < 8; ++j) acc[i][j] = 0.f;

    const float* Xb = H1raw + (size_t)b * 32 * 1024 * 128;
    for (int ry = 0; ry < 3; ++ry) {
        const int gy = (y + ry + 31) & 31;
        const float* Xrow = Xb + (size_t)gy * 1024 * 128;
        for (int cc = 0; cc < 128; cc += 32) {
            __syncthreads();
            // A: 66 xx x 8 c4 = 528 f4, GN1+gelu, transpose to [ci][xx]
            for (int f = tid; f < 528; f += 256) {
                int xx = f >> 3, c4 = f & 7;
                int gx = (x0 + xx + 1023) & 1023;
                float4 v = *(const float4*)(Xrow + (size_t)gx * 128 + cc + c4 * 4);
                int c = cc + c4 * 4;
                As[c4 * 4 + 0][xx] = gelu_f(v.x * ns[c + 0] + nb[c + 0]);
                As[c4 * 4 + 1][xx] = gelu_f(v.y * ns[c + 1] + nb[c + 1]);
                As[c4 * 4 + 2][xx] = gelu_f(v.z * ns[c + 2] + nb[c + 2]);
                As[c4 * 4 + 3][xx] = gelu_f(v.w * ns[c + 3] + nb[c + 3]);
            }
            // W: 3 dx x 32 ci x 16 o4 = 1536 f4
            for (int f = tid; f < 1536; f += 256) {
                int o4 = f & 15, ci = (f >> 4) & 31, dx = f >> 9;
                *(float4*)&Ws[dx][ci][o4 * 4] =
                    *(const float4*)(Wc + ((size_t)(ry * 3 + dx) * 128 + cc + ci) * 64 + o4 * 4);
            }
            __syncthreads();
#pragma unroll 2
            for (int kk = 0; kk < 8; ++kk) {
                const int k = ks * 8 + kk;
                const float4 a0 = *(const float4*)&As[k][pg * 8 + 0];
                const float4 a1 = *(const float4*)&As[k][pg * 8 + 4];
                const float4 a2 = *(const float4*)&As[k][pg * 8 + 8];
                const float r[12] = {a0.x, a0.y, a0.z, a0.w, a1.x, a1.y, a1.z, a1.w,
                                     a2.x, a2.y, a2.z, a2.w};
#pragma unroll
                for (int dx = 0; dx < 3; ++dx) {
                    const float4 w0 = *(const float4*)&Ws[dx][k][og * 8];
                    const float4 w1 = *(const float4*)&Ws[dx][k][og * 8 + 4];
                    const float wv[8] = {w0.x, w0.y, w0.z, w0.w, w1.x, w1.y, w1.z, w1.w};
#pragma unroll
                    for (int i = 0; i < 8; ++i)
#pragma unroll
                        for (int j = 0; j < 8; ++j) acc[i][j] += r[i + dx] * wv[j];
                }
            }
        }
    }
    // reduce 4 k-splits -> split 0 (reuse Ws as 6144-float buffer)
    float* rbuf = &Ws[0][0][0];
    const int cell = pg * 8 + og;
#pragma unroll
    for (int half = 0; half < 2; ++half) {
        __syncthreads();
        if (ks > 0) {
#pragma unroll
            for (int i = 0; i < 8; ++i)
                *(float4*)&rbuf[(((ks - 1) * 64 + cell) * 8 + i) * 4] =
                    make_float4(acc[i][half * 4 + 0], acc[i][half * 4 + 1],
                                acc[i][half * 4 + 2], acc[i][half * 4 + 3]);
        }
        __syncthreads();
        if (ks == 0) {
#pragma unroll
            for (int s = 0; s < 3; ++s)
#pragma unroll
                for (int i = 0; i < 8; ++i) {
                    float4 v = *(const float4*)&rbuf[((s * 64 + cell) * 8 + i) * 4];
                    acc[i][half * 4 + 0] += v.x;
                    acc[i][half * 4 + 1] += v.y;
                    acc[i][half * 4 + 2] += v.z;
                    acc[i][half * 4 + 3] += v.w;
                }
        }
    }
    if (ks == 0) {  // wave 0 holds final sums: GN2 stats + store
        float s = 0.f, q = 0.f;
#pragma unroll
        for (int i = 0; i < 8; ++i)
#pragma unroll
            for (int j = 0; j < 8; ++j) { s += acc[i][j]; q += acc[i][j] * acc[i][j]; }
#pragma unroll
        for (int mk = 8; mk < 64; mk <<= 1) {
            s += __shfl_xor(s, mk);
            q += __shfl_xor(q, mk);
        }
        if (tid < 8) {
            atomicAdd(&stats2[(b * 8 + tid) * 2 + 0], s);
            atomicAdd(&stats2[(b * 8 + tid) * 2 + 1], q);
        }
#pragma unroll
        for (int i = 0; i < 8; ++i) {
            int x = x0 + pg * 8 + i;
            float* yp = Y + (((size_t)(b * 32 + y) * 1024 + x) * 64 + og * 8);
            *(float4*)(yp + 0) = make_float4(acc[i][0], acc[i][1], acc[i][2], acc[i][3]);
            *(float4*)(yp + 4) = make_float4(acc[i][4], acc[i][5], acc[i][6], acc[i][7]);
        }
    }
}

// ---------------- fused GN2-apply + GELU + rh3 head ----------------
__global__ __launch_bounds__(256) void rh3_kernel(
    const float* __restrict__ H2, const float* __restrict__ stats,
    const float* __restrict__ gamma, const float* __restrict__ beta, float inv_cnt,
    const float* __restrict__ w3, const float* __restrict__ b3,
    const float2* __restrict__ azsc,
    float2* __restrict__ refxy, float2* __restrict__ sigf) {
    const int tid = threadIdx.x;
    const int lane = tid & 15;
    const int m = blockIdx.x * 16 + (tid >> 4);
    const int b = m >> 15;
    const int c = lane * 4;
    const int g = c >> 3;
    float mean = stats[(b * 8 + g) * 2 + 0] * inv_cnt;
    float var = stats[(b * 8 + g) * 2 + 1] * inv_cnt - mean * mean;
    float rs = 1.0f / sqrtf(var + 1e-5f);
    float4 v = *(const float4*)(H2 + (size_t)m * 64 + c);
    float hv[4];
    hv[0] = gelu_f((v.x - mean) * rs * gamma[c + 0] + beta[c + 0]);
    hv[1] = gelu_f((v.y - mean) * rs * gamma[c + 1] + beta[c + 1]);
    hv[2] = gelu_f((v.z - mean) * rs * gamma[c + 2] + beta[c + 2]);
    hv[3] = gelu_f((v.w - mean) * rs * gamma[c + 3] + beta[c + 3]);
    float d0 = 0.f, d1 = 0.f;
#pragma unroll
    for (int k = 0; k < 4; ++k) {
        d0 += hv[k] * w3[(c + k) * 2 + 0];
        d1 += hv[k] * w3[(c + k) * 2 + 1];
    }
#pragma unroll
    for (int s = 1; s < 16; s <<= 1) {
        d0 += __shfl_xor(d0, s, 16);
        d1 += __shfl_xor(d1, s, 16);
    }
    if (lane == 0) {
        float mu = fminf(fmaxf(d0 + b3[0], 0.f), 55.f);
        float ls = fminf(fmaxf(d1 + b3[1], -5.f), 3.f);
        float sg = expf(ls);
        float2 sc = azsc[m & 1023];
        float rx = fminf(fmaxf(mu * sc.y * 0.01f + 0.5f, 0.f), 1.f);
        float ry = fminf(fmaxf(mu * sc.x * 0.01f + 0.5f, 0.f), 1.f);
        refxy[m] = make_float2(rx, ry);
        sigf[m] = make_float2(ls, 1.f / (sg + 1e-6f));
    }
}

// ---------------- MSDA bilinear sampling ----------------
__device__ __forceinline__ float samp_v(const float* __restrict__ Vb, int x, int y) {
    bool valid = ((unsigned)x < 200u) && ((unsigned)y < 200u);
    int xc = min(max(x, 0), 199);
    int yc = min(max(y, 0), 199);
    float v = Vb[((size_t)yc * 200 + xc) * 128];
    return valid ? v : 0.f;
}

__global__ __launch_bounds__(256) void msda_kernel(
    const float* __restrict__ V, const float2* __restrict__ refxy,
    const float* __restrict__ offs, const float* __restrict__ aw,
    float* __restrict__ out) {
    const int tid = threadIdx.x;
    const int lane = tid & 15;
    const int grp = tid >> 4;
    const int m = blockIdx.x * 2 + (grp >> 3);
    const int head = grp & 7;
    const int b = m >> 15;
    float2 r = refxy[m];
    const float* lg = aw + (size_t)m * 48 + head * 6;
    float l[6];
#pragma unroll
    for (int p = 0; p < 6; ++p) l[p] = lg[p];
    float mx = l[0];
#pragma unroll
    for (int p = 1; p < 6; ++p) mx = fmaxf(mx, l[p]);
    float s = 0.f;
#pragma unroll
    for (int p = 0; p < 6; ++p) { l[p] = expf(l[p] - mx); s += l[p]; }
    float inv = 1.f / s;
    const float* of = offs + (size_t)m * 96 + head * 12;
    const float* Vb = V + (size_t)b * 40000 * 128 + head * 16 + lane;
    float acc = 0.f;
#pragma unroll
    for (int p = 0; p < 6; ++p) {
        float px = r.x * 200.f + of[p * 2 + 0] - 0.5f;
        float py = r.y * 200.f + of[p * 2 + 1] - 0.5f;
        float fx = floorf(px), fy = floorf(py);
        int x0 = (int)fx, y0 = (int)fy;
        float wx = px - fx, wy = py - fy;
        float v00 = samp_v(Vb, x0, y0);
        float v10 = samp_v(Vb, x0 + 1, y0);
        float v01 = samp_v(Vb, x0, y0 + 1);
        float v11 = samp_v(Vb, x0 + 1, y0 + 1);
        float bil = v00 * (1.f - wx) * (1.f - wy) + v10 * wx * (1.f - wy) +
                    v01 * (1.f - wx) * wy + v11 * wx * wy;
        acc += l[p] * inv * bil;
    }
    out[(size_t)m * 128 + head * 16 + lane] = acc;
}

// ---------------- launch ----------------
extern "C" void kernel_launch(void* const* d_in, const int* in_sizes, int n_in,
                              void* d_out, int out_size, void* d_ws, size_t ws_size,
                              hipStream_t stream) {
    const float* x_rv = (const float*)d_in[0];
    const float* bev = (const float*)d_in[1];
    const float* pq_w = (const float*)d_in[2];
    const float* pq_b = (const float*)d_in[3];
    const float* pv_w = (const float*)d_in[4];
    const float* pv_b = (const float*)d_in[5];
    const float* po_w = (const float*)d_in[6];
    const float* po_b = (const float*)d_in[7];
    const float* qs_w1 = (const float*)d_in[8];
    const float* qs_b1 = (const float*)d_in[9];
    const float* qs_w2 = (const float*)d_in[10];
    const float* qs_b2 = (const float*)d_in[11];
    const float* rh_w1 = (const float*)d_in[12];
    const float* rh_b1 = (const float*)d_in[13];
    const float* rh_g1 = (const float*)d_in[14];
    const float* rh_be1 = (const float*)d_in[15];
    const float* rh_w2 = (const float*)d_in[16];
    const float* rh_g2 = (const float*)d_in[17];
    const float* rh_be2 = (const float*)d_in[18];
    const float* rh_w3 = (const float*)d_in[19];
    const float* rh_b3 = (const float*)d_in[20];
    const float* so_w = (const float*)d_in[21];
    const float* so_b = (const float*)d_in[22];
    const float* aw_w = (const float*)d_in[23];
    const float* aw_b = (const float*)d_in[24];
    const float* vp_w = (const float*)d_in[25];
    const float* vp_b = (const float*)d_in[26];
    const float* op_w = (const float*)d_in[27];
    const float* op_b = (const float*)d_in[28];

    const int M = 65536;

    float* ws = (float*)d_ws;
    float* azsc = ws;    ws += 2048;
    float* pvvp_w = ws;  ws += 256 * 128;
    float* pvvp_b = ws;  ws += 128;
    float* oppo_w = ws;  ws += 128 * 128;
    float* oppo_b = ws;  ws += 128;
    float* pqqs_w = ws;  ws += 64 * 128;
    float* pqqs_b = ws;  ws += 128;
    float* qsso_w = ws;  ws += 128 * 96;
    float* qsso_b = ws;  ws += 128;
    float* qsaw_w = ws;  ws += 128 * 48;
    float* qsaw_b = ws;  ws += 64;
    float* stats = ws;   ws += 64;   // [0:32) GN1, [32:64) GN2
    float* Vv = ws;      ws += (size_t)80000 * 128;
    float* h1 = ws;      ws += (size_t)M * 128;
    float* h2 = ws;      ws += (size_t)M * 64;
    float* q1 = ws;      ws += (size_t)M * 128;
    float* refxy = ws;   ws += (size_t)M * 2;
    float* sigf = ws;    ws += (size_t)M * 2;
    size_t need_bytes = (size_t)(ws - (float*)d_ws) * sizeof(float);
    if (ws_size < need_bytes) return;
    float* offs = h1;   // h1 (raw rh1) dead after conv; M*96 <= M*128
    float* attw = h2;   // h2 dead after rh3; M*48 <= M*64
    float* mo = q1;     // q1 dead after offs/attw GEMMs

    float2* azsc2 = (float2*)azsc;
    float2* refxy2 = (float2*)refxy;
    float2* sigf2 = (float2*)sigf;

    prep_weights<<<717, 128, 0, stream>>>(
        pv_w, pv_b, vp_w, vp_b, op_w, op_b, po_w, po_b, pq_w, pq_b,
        qs_w1, qs_b1, qs_w2, qs_b2, so_w, so_b, aw_w, aw_b,
        pvvp_w, pvvp_b, oppo_w, oppo_b, pqqs_w, pqqs_b,
        qsso_w, qsso_b, qsaw_w, qsaw_b, azsc2);
    hipMemsetAsync(stats, 0, 64 * sizeof(float), stream);

    // h1 = raw rh1 (x_rv(+az) @ rh_w1 + b); fused GN1 stats
    gemm_v3<128, true><<<M / 128, 256, 0, stream>>>(
        x_rv, 64, rh_w1, rh_b1, h1, 64, azsc2, nullptr, rh_w1 + 64 * 128, 1, 0, stats);

    // value = bev^T @ (pv_w@vp_w) + fused bias
    value_gemm<<<dim3(313, 2), 256, 0, stream>>>(bev, pvvp_w, pvvp_b, Vv);

    // conv (GN1-apply+gelu in staging, GN2 stats in epilogue)
    conv3x3_v4<<<dim3(16, 32, 2), 256, 0, stream>>>(h1, stats, rh_g1, rh_be1,
                                                    rh_w2, h2, stats + 32);

    // fused GN2-apply + gelu + rh3 head
    rh3_kernel<<<4096, 256, 0, stream>>>(h2, stats + 32, rh_g2, rh_be2, 1.0f / 262144.0f,
                                         rh_w3, rh_b3, azsc2, refxy2, sigf2);

    // q1 = gelu(x_rv @ (pq_w@qs_w1a) + sigf extras + fused bias)
    gemm_v3<128, false><<<M / 128, 256, 0, stream>>>(
        x_rv, 64, pqqs_w, pqqs_b, q1, 64, nullptr, sigf, qs_w1 + 128 * 128, 2, 1, nullptr);

    // offs = q1 @ (qs_w2@so_w) + folded bias   [query GEMM eliminated]
    gemm_v3<96, false><<<M / 128, 192, 0, stream>>>(
        q1, 128, qsso_w, qsso_b, offs, 128, nullptr, nullptr, nullptr, 0, 0, nullptr);

    // attw logits = q1 @ (qs_w2@aw_w) + folded bias
    gemm_rn<128, 48, 192><<<M / 128, 192, 0, stream>>>(
        q1, 128, qsaw_w, 48, qsaw_b, attw, 48, 128);

    // MSDA sampling (into q1)
    msda_kernel<<<M / 2, 256, 0, stream>>>(Vv, refxy2, offs, attw, mo);

    // y = mo @ (op_w@po_w) + fused bias -> d_out
    gemm_v3<128, false><<<M / 128, 256, 0, stream>>>(
        mo, 128, oppo_w, oppo_b, (float*)d_out, 128, nullptr, nullptr, nullptr, 0, 0, nullptr);
}

// Round 6
// 559.150 us; speedup vs baseline: 1.8842x; 1.1707x over previous
//
#include <hip/hip_runtime.h>
#include <math.h>

#define PI_F 3.14159265358979323846f

// ---- static config ----
// B=2, HRV=32, WRV=1024, CRV=64; CB=256, HB=200, WB=200
// D=128, COUT=128, HEADS=8, POINTS=6, DH=16; M=65536, NV=40000
//
// Hard-won rules (rounds 1-5):
//  - >=8-16 waves/CU or latency kills you (grid/256 * waves_per_block).
//  - fp32: FMA per LDS-float >= 4 (LDS 32 fl/cyc vs 128 FMA/cyc per CU).
//  - LDS row stride: pick so consecutive rows land on distinct bank groups;
//    keep 16B alignment for b128 (bf16 rows padded to 40 elems = 80 B).
//  - conv is MFMA-shaped; bf16 error is attenuated ~1000x before y (only
//    feeds mu/sigma/ref). Value path must stay fp32.

typedef __attribute__((ext_vector_type(8))) short bf16x8;
typedef __attribute__((ext_vector_type(4))) float f32x4;

__device__ __forceinline__ float gelu_f(float x) {
    return 0.5f * x * (1.0f + erff(x * 0.70710678118654752440f));
}

__device__ __forceinline__ unsigned short f2bf(float x) {
    unsigned int u = __float_as_uint(x);
    u += 0x7fffu + ((u >> 16) & 1u);  // RNE
    return (unsigned short)(u >> 16);
}

// ---------------- fused weight prep (+ az table + bf16 conv weights) -------
__global__ void prep_weights(const float* __restrict__ pv_w, const float* __restrict__ pv_b,
                             const float* __restrict__ vp_w, const float* __restrict__ vp_b,
                             const float* __restrict__ op_w, const float* __restrict__ op_b,
                             const float* __restrict__ po_w, const float* __restrict__ po_b,
                             const float* __restrict__ pq_w, const float* __restrict__ pq_b,
                             const float* __restrict__ qs_w1, const float* __restrict__ qs_b1,
                             const float* __restrict__ qs_w2, const float* __restrict__ qs_b2,
                             const float* __restrict__ so_w, const float* __restrict__ so_b,
                             const float* __restrict__ aw_w, const float* __restrict__ aw_b,
                             const float* __restrict__ rh_w2,
                             float* __restrict__ pvvp_w, float* __restrict__ pvvp_b,
                             float* __restrict__ oppo_w, float* __restrict__ oppo_b,
                             float* __restrict__ pqqs_w, float* __restrict__ pqqs_b,
                             float* __restrict__ qsso_w, float* __restrict__ qsso_b,
                             float* __restrict__ qsaw_w, float* __restrict__ qsaw_b,
                             unsigned short* __restrict__ wtb,
                             float2* __restrict__ azsc) {
    int r = blockIdx.x;
    int d = threadIdx.x; // 0..127
    if (r < 256) {
        float s = 0.f;
        for (int k = 0; k < 128; ++k) s += pv_w[r * 128 + k] * vp_w[k * 128 + d];
        pvvp_w[r * 128 + d] = s;
    } else if (r == 256) {
        float s = vp_b[d];
        for (int k = 0; k < 128; ++k) s += pv_b[k] * vp_w[k * 128 + d];
        pvvp_b[d] = s;
    } else if (r < 385) {
        int rr = r - 257;
        float s = 0.f;
        for (int k = 0; k < 128; ++k) s += op_w[rr * 128 + k] * po_w[k * 128 + d];
        oppo_w[rr * 128 + d] = s;
    } else if (r == 385) {
        float s = po_b[d];
        for (int k = 0; k < 128; ++k) s += op_b[k] * po_w[k * 128 + d];
        oppo_b[d] = s;
    } else if (r < 450) {
        int rr = r - 386;
        float s = 0.f;
        for (int k = 0; k < 128; ++k) s += pq_w[rr * 128 + k] * qs_w1[k * 128 + d];
        pqqs_w[rr * 128 + d] = s;
    } else if (r == 450) {
        float s = qs_b1[d];
        for (int k = 0; k < 128; ++k) s += pq_b[k] * qs_w1[k * 128 + d];
        pqqs_b[d] = s;
    } else if (r < 459) {
        int w = (r - 451) * 128 + d;
        float az = -PI_F + (float)w * (6.283185307179586f / 1024.0f);
        azsc[w] = make_float2(sinf(az), cosf(az));
    } else if (r < 587) {
        int rr = r - 459;
        if (d < 96) {
            float s = 0.f;
            for (int k = 0; k < 128; ++k) s += qs_w2[rr * 128 + k] * so_w[k * 96 + d];
            qsso_w[rr * 96 + d] = s;
        }
    } else if (r == 587) {
        if (d < 96) {
            float s = so_b[d];
            for (int k = 0; k < 128; ++k) s += qs_b2[k] * so_w[k * 96 + d];
            qsso_b[d] = s;
        }
    } else if (r < 716) {
        int rr = r - 588;
        if (d < 48) {
            float s = 0.f;
            for (int k = 0; k < 128; ++k) s += qs_w2[rr * 128 + k] * aw_w[k * 48 + d];
            qsaw_w[rr * 48 + d] = s;
        }
    } else if (r == 716) {
        if (d < 48) {
            float s = aw_b[d];
            for (int k = 0; k < 128; ++k) s += qs_b2[k] * aw_w[k * 48 + d];
            qsaw_b[d] = s;
        }
    } else {
        // conv weights -> bf16, transposed: wtb[tap][cc4][o][ci]
        int idx = (r - 717) * 128 + d;   // 0 .. 73727
        int ci = idx & 31;
        int o = (idx >> 5) & 63;
        int cc4i = (idx >> 11) & 3;
        int tap = idx >> 13;
        float w = rh_w2[((size_t)tap * 128 + cc4i * 32 + ci) * 64 + o];
        wtb[idx] = f2bf(w);
    }
}

// ---------------- MT=128 GEMM, 8x8 micro, 2*NT threads ----------------
template <int NT, bool STATS>
__global__ __launch_bounds__(2 * NT) void gemm_v3(
    const float* __restrict__ A, int lda,
    const float* __restrict__ W,
    const float* __restrict__ bias,
    float* __restrict__ C, int K,
    const float2* __restrict__ azsc,
    const float* __restrict__ extra2,
    const float* __restrict__ extra_w,
    int emode, int do_gelu, float* __restrict__ stats1) {
    constexpr int NTH = 2 * NT;
    constexpr int NTO = NT / 8;
    __shared__ float As[32][140];   // 140 % 32 = 12 -> conflict-free scatter
    __shared__ float Ws[32][NT];
    __shared__ float sred[8][2];
    const int tid = threadIdx.x;
    const int tn = tid % NTO;
    const int tm = tid / NTO;   // 0..15
    const int m0 = blockIdx.x * 128;
    if (STATS && tid < 16) sred[tid >> 1][tid & 1] = 0.f;
    float acc[8][8];
#pragma unroll
    for (int i = 0; i < 8; ++i)
#pragma unroll
        for (int j = 0; j < 8; ++j) acc[i][j] = 0.f;

    for (int k0 = 0; k0 < K; k0 += 32) {
        __syncthreads();
        for (int f = tid; f < 1024; f += NTH) {
            int r = f >> 3, c4 = f & 7;
            float4 v = *(const float4*)(A + (size_t)(m0 + r) * lda + k0 + c4 * 4);
            As[c4 * 4 + 0][r] = v.x;
            As[c4 * 4 + 1][r] = v.y;
            As[c4 * 4 + 2][r] = v.z;
            As[c4 * 4 + 3][r] = v.w;
        }
        for (int f = tid; f < 8 * NT; f += NTH) {
            int kk = f / (NT / 4), n4 = f % (NT / 4);
            *(float4*)&Ws[kk][n4 * 4] = *(const float4*)(W + (size_t)(k0 + kk) * NT + n4 * 4);
        }
        __syncthreads();
#pragma unroll 2
        for (int k = 0; k < 32; ++k) {
            const float4 a0 = *(const float4*)&As[k][tm * 8];
            const float4 a1 = *(const float4*)&As[k][tm * 8 + 4];
            const float4 w0 = *(const float4*)&Ws[k][tn * 8];
            const float4 w1 = *(const float4*)&Ws[k][tn * 8 + 4];
            const float av[8] = {a0.x, a0.y, a0.z, a0.w, a1.x, a1.y, a1.z, a1.w};
            const float wv[8] = {w0.x, w0.y, w0.z, w0.w, w1.x, w1.y, w1.z, w1.w};
#pragma unroll
            for (int i = 0; i < 8; ++i)
#pragma unroll
                for (int j = 0; j < 8; ++j) acc[i][j] += av[i] * wv[j];
        }
    }
    float bv[8], e0w[8], e1w[8];
#pragma unroll
    for (int j = 0; j < 8; ++j) bv[j] = bias[tn * 8 + j];
    if (emode) {
#pragma unroll
        for (int j = 0; j < 8; ++j) {
            e0w[j] = extra_w[tn * 8 + j];
            e1w[j] = extra_w[NT + tn * 8 + j];
        }
    }
    float ts = 0.f, ts2 = 0.f;
#pragma unroll
    for (int i = 0; i < 8; ++i) {
        int m = m0 + tm * 8 + i;
        float e0 = 0.f, e1 = 0.f;
        if (emode == 1) {
            float2 sc = azsc[m & 1023];
            e0 = sc.x; e1 = sc.y;
        } else if (emode == 2) {
            e0 = extra2[2 * (size_t)m];
            e1 = extra2[2 * (size_t)m + 1];
        }
        float o[8];
#pragma unroll
        for (int j = 0; j < 8; ++j) {
            float v = acc[i][j] + bv[j];
            if (emode) v += e0 * e0w[j] + e1 * e1w[j];
            if (do_gelu) v = gelu_f(v);
            if (STATS) { ts += v; ts2 += v * v; }
            o[j] = v;
        }
        *(float4*)(C + (size_t)m * NT + tn * 8) = make_float4(o[0], o[1], o[2], o[3]);
        *(float4*)(C + (size_t)m * NT + tn * 8 + 4) = make_float4(o[4], o[5], o[6], o[7]);
    }
    if (STATS) {  // C=128, CPG=16: thread's 8 cols lie in group tn>>1
        atomicAdd(&sred[tn >> 1][0], ts);
        atomicAdd(&sred[tn >> 1][1], ts2);
        __syncthreads();
        if (tid < 8) {
            int b = m0 >> 15;
            atomicAdd(&stats1[(b * 8 + tid) * 2 + 0], sred[tid][0]);
            atomicAdd(&stats1[(b * 8 + tid) * 2 + 1], sred[tid][1]);
        }
    }
}

// ---------------- small-NT GEMM (8x4 micro) for attw ----------------
template <int MT, int NT, int NTH>
__global__ __launch_bounds__(NTH) void gemm_rn(
    const float* __restrict__ A, int lda,
    const float* __restrict__ W, int ldw,
    const float* __restrict__ bias,
    float* __restrict__ C, int ldc, int K) {
    static_assert(NTH == (MT / 8) * (NT / 4), "thread count mismatch");
    __shared__ float As[32][MT + 12];
    __shared__ float Ws[32][NT];
    constexpr int NTN = NT / 4;
    const int tid = threadIdx.x;
    const int tn = tid % NTN;
    const int tm = tid / NTN;
    const int m0 = blockIdx.x * MT;
    float acc[8][4];
#pragma unroll
    for (int i = 0; i < 8; ++i)
#pragma unroll
        for (int j = 0; j < 4; ++j) acc[i][j] = 0.f;

    for (int k0 = 0; k0 < K; k0 += 32) {
        __syncthreads();
        for (int f = tid; f < MT * 8; f += NTH) {
            int r = f >> 3, c4 = f & 7;
            float4 v = *(const float4*)(A + (size_t)(m0 + r) * lda + k0 + c4 * 4);
            As[c4 * 4 + 0][r] = v.x;
            As[c4 * 4 + 1][r] = v.y;
            As[c4 * 4 + 2][r] = v.z;
            As[c4 * 4 + 3][r] = v.w;
        }
        for (int f = tid; f < 8 * NT; f += NTH) {
            int kk = f / NTN, n4 = f % NTN;
            *(float4*)&Ws[kk][n4 * 4] = *(const float4*)(W + (size_t)(k0 + kk) * ldw + n4 * 4);
        }
        __syncthreads();
#pragma unroll 4
        for (int k = 0; k < 32; ++k) {
            const float4 a0 = *(const float4*)&As[k][tm * 8];
            const float4 a1 = *(const float4*)&As[k][tm * 8 + 4];
            const float4 wv = *(const float4*)&Ws[k][tn * 4];
            acc[0][0] += a0.x * wv.x; acc[0][1] += a0.x * wv.y; acc[0][2] += a0.x * wv.z; acc[0][3] += a0.x * wv.w;
            acc[1][0] += a0.y * wv.x; acc[1][1] += a0.y * wv.y; acc[1][2] += a0.y * wv.z; acc[1][3] += a0.y * wv.w;
            acc[2][0] += a0.z * wv.x; acc[2][1] += a0.z * wv.y; acc[2][2] += a0.z * wv.z; acc[2][3] += a0.z * wv.w;
            acc[3][0] += a0.w * wv.x; acc[3][1] += a0.w * wv.y; acc[3][2] += a0.w * wv.z; acc[3][3] += a0.w * wv.w;
            acc[4][0] += a1.x * wv.x; acc[4][1] += a1.x * wv.y; acc[4][2] += a1.x * wv.z; acc[4][3] += a1.x * wv.w;
            acc[5][0] += a1.y * wv.x; acc[5][1] += a1.y * wv.y; acc[5][2] += a1.y * wv.z; acc[5][3] += a1.y * wv.w;
            acc[6][0] += a1.z * wv.x; acc[6][1] += a1.z * wv.y; acc[6][2] += a1.z * wv.z; acc[6][3] += a1.z * wv.w;
            acc[7][0] += a1.w * wv.x; acc[7][1] += a1.w * wv.y; acc[7][2] += a1.w * wv.z; acc[7][3] += a1.w * wv.w;
        }
    }
#pragma unroll
    for (int i = 0; i < 8; ++i) {
        int m = m0 + tm * 8 + i;
        float4 o;
        o.x = acc[i][0] + bias[tn * 4 + 0];
        o.y = acc[i][1] + bias[tn * 4 + 1];
        o.z = acc[i][2] + bias[tn * 4 + 2];
        o.w = acc[i][3] + bias[tn * 4 + 3];
        *(float4*)(C + (size_t)m * ldc + tn * 4) = o;
    }
}

// ---------------- value GEMM (A = bev^T strided), 256 thr ----------------
__global__ __launch_bounds__(256) void value_gemm(
    const float* __restrict__ bev, const float* __restrict__ Wf,
    const float* __restrict__ bf, float* __restrict__ V) {
    __shared__ float As[32][140];   // [k][n] natural layout
    __shared__ float Ws[32][128];   // [k][d]
    const int tid = threadIdx.x;
    const int tn = tid & 15;
    const int tm = tid >> 4;  // 0..15
    const int n0 = blockIdx.x * 128;
    const int b = blockIdx.y;
    const float* bevb = bev + (size_t)b * 256 * 40000;
    float acc[8][8];
#pragma unroll
    for (int i = 0; i < 8; ++i)
#pragma unroll
        for (int j = 0; j < 8; ++j) acc[i][j] = 0.f;

    for (int k0 = 0; k0 < 256; k0 += 32) {
        __syncthreads();
        for (int f = tid; f < 1024; f += 256) {
            int kk = f >> 5, n4 = f & 31;
            int nl = n0 + n4 * 4;
            nl = nl > 39996 ? 39996 : nl;
            *(float4*)&As[kk][n4 * 4] = *(const float4*)(bevb + (size_t)(k0 + kk) * 40000 + nl);
        }
        for (int f = tid; f < 1024; f += 256) {
            int kk = f >> 5, n4 = f & 31;
            *(float4*)&Ws[kk][n4 * 4] = *(const float4*)(Wf + (size_t)(k0 + kk) * 128 + n4 * 4);
        }
        __syncthreads();
#pragma unroll 2
        for (int k = 0; k < 32; ++k) {
            const float4 a0 = *(const float4*)&As[k][tm * 8];
            const float4 a1 = *(const float4*)&As[k][tm * 8 + 4];
            const float4 w0 = *(const float4*)&Ws[k][tn * 8];
            const float4 w1 = *(const float4*)&Ws[k][tn * 8 + 4];
            const float av[8] = {a0.x, a0.y, a0.z, a0.w, a1.x, a1.y, a1.z, a1.w};
            const float wv[8] = {w0.x, w0.y, w0.z, w0.w, w1.x, w1.y, w1.z, w1.w};
#pragma unroll
            for (int i = 0; i < 8; ++i)
#pragma unroll
                for (int j = 0; j < 8; ++j) acc[i][j] += av[i] * wv[j];
        }
    }
    float bv[8];
#pragma unroll
    for (int j = 0; j < 8; ++j) bv[j] = bf[tn * 8 + j];
#pragma unroll
    for (int i = 0; i < 8; ++i) {
        int n = n0 + tm * 8 + i;
        if (n < 40000) {
            float o[8];
#pragma unroll
            for (int j = 0; j < 8; ++j) o[j] = acc[i][j] + bv[j];
            float* vp = V + ((size_t)b * 40000 + n) * 128 + tn * 8;
            *(float4*)(vp + 0) = make_float4(o[0], o[1], o[2], o[3]);
            *(float4*)(vp + 4) = make_float4(o[4], o[5], o[6], o[7]);
        }
    }
}

// ---------------- GN1 apply + GELU -> bf16 ----------------
__global__ __launch_bounds__(256) void gn1_bf16(
    const float* __restrict__ X, const float* __restrict__ stats,
    const float* __restrict__ g1, const float* __restrict__ be1,
    unsigned short* __restrict__ Ob) {
    size_t i4 = (size_t)blockIdx.x * 256 + threadIdx.x;
    size_t base = i4 * 4;
    int c = (int)(base & 127);
    int mrow = (int)(base >> 7);
    int b = mrow >> 15;
    int g = c >> 4;
    float mean = stats[(b * 8 + g) * 2 + 0] * (1.0f / 524288.0f);
    float var = stats[(b * 8 + g) * 2 + 1] * (1.0f / 524288.0f) - mean * mean;
    float rs = 1.0f / sqrtf(var + 1e-5f);
    float4 x = *(const float4*)(X + base);
    float4 gm = *(const float4*)(g1 + c);
    float4 bt = *(const float4*)(be1 + c);
    ushort4 o;
    o.x = f2bf(gelu_f((x.x - mean) * rs * gm.x + bt.x));
    o.y = f2bf(gelu_f((x.y - mean) * rs * gm.y + bt.y));
    o.z = f2bf(gelu_f((x.z - mean) * rs * gm.z + bt.z));
    o.w = f2bf(gelu_f((x.w - mean) * rs * gm.w + bt.w));
    *(ushort4*)(Ob + base) = o;
}

// ---------------- 3x3 circular conv via bf16 MFMA ----------------
// Block: 64 px x 64 out, 4 waves (wave w: px w*16..+15, all 64 out as 4 C-frags).
// K = 9 taps x 128 ci, chunked (ry, cc=32). Per chunk per wave:
// 3 dx x (1 A-frag + 4 B-frag reads + 4 MFMA). GN2 stats in epilogue.
// mfma_f32_16x16x32_bf16: A[m=lane&15][k=quad*8+j]; B[k=quad*8+j][n=lane&15];
// D col=lane&15, row=quad*4+reg. LDS bf16 rows padded to 40 elems (80 B).
__global__ __launch_bounds__(256, 4) void conv3x3_mfma(
    const unsigned short* __restrict__ H1b,  // [2][32][1024][128] bf16
    const unsigned short* __restrict__ Wtb,  // [9][4][64][32] bf16
    float* __restrict__ Y,                   // [2][32][1024][64]
    float* __restrict__ stats2) {
    __shared__ short As_s[66 * 40];      // [xx][ci_chunk] 5.2 KB
    __shared__ short Ws_s[3 * 64 * 40];  // [dx][o][ci_chunk] 15.4 KB
    __shared__ float sred[8][2];
    const int tid = threadIdx.x;
    const int wid = tid >> 6;
    const int lane = tid & 63;
    const int m = lane & 15;
    const int quad = lane >> 4;
    const int x0 = blockIdx.x * 64;
    const int y = blockIdx.y;
    const int b = blockIdx.z;
    if (tid < 16) sred[tid >> 1][tid & 1] = 0.f;
    f32x4 acc[4];
#pragma unroll
    for (int oq = 0; oq < 4; ++oq) acc[oq] = (f32x4){0.f, 0.f, 0.f, 0.f};

    const unsigned short* Hb = H1b + (size_t)b * 32 * 1024 * 128;
    for (int ry = 0; ry < 3; ++ry) {
        const int gy = (y + ry + 31) & 31;
        const unsigned short* Hrow = Hb + (size_t)gy * 1024 * 128;
        for (int cc4 = 0; cc4 < 4; ++cc4) {
            __syncthreads();
            // A: 66 xx-rows x 4 octets of 8 bf16 = 264 16B chunks
            for (int f = tid; f < 264; f += 256) {
                int xx = f >> 2, cq = f & 3;
                int gx = (x0 + xx + 1023) & 1023;
                uint4 v = *(const uint4*)(Hrow + (size_t)gx * 128 + cc4 * 32 + cq * 8);
                *(uint4*)&As_s[xx * 40 + cq * 8] = v;
            }
            // W: 3 dx x 64 o x 4 octets = 768 16B chunks
            for (int f = tid; f < 768; f += 256) {
                int cq = f & 3, o = (f >> 2) & 63, dx = f >> 8;
                int tap = ry * 3 + dx;
                uint4 v = *(const uint4*)(Wtb + ((size_t)(tap * 4 + cc4) * 64 + o) * 32 + cq * 8);
                *(uint4*)&Ws_s[(dx * 64 + o) * 40 + cq * 8] = v;
            }
            __syncthreads();
            const int arow = wid * 16 + m;
#pragma unroll
            for (int dx = 0; dx < 3; ++dx) {
                bf16x8 a = *(const bf16x8*)&As_s[(arow + dx) * 40 + quad * 8];
#pragma unroll
                for (int oq = 0; oq < 4; ++oq) {
                    bf16x8 bfr = *(const bf16x8*)&Ws_s[(dx * 64 + oq * 16 + m) * 40 + quad * 8];
                    acc[oq] = __builtin_amdgcn_mfma_f32_16x16x32_bf16(a, bfr, acc[oq], 0, 0, 0);
                }
            }
        }
    }
    // GN2 stats: lane's frag oq covers o = oq*16 + m -> group oq*2 + (m>>3)
    float sv[4], qv[4];
#pragma unroll
    for (int oq = 0; oq < 4; ++oq) {
        sv[oq] = acc[oq].x + acc[oq].y + acc[oq].z + acc[oq].w;
        qv[oq] = acc[oq].x * acc[oq].x + acc[oq].y * acc[oq].y +
                 acc[oq].z * acc[oq].z + acc[oq].w * acc[oq].w;
    }
    const int masks[5] = {1, 2, 4, 16, 32};  // reduce over all but bit3
#pragma unroll
    for (int mi = 0; mi < 5; ++mi) {
#pragma unroll
        for (int oq = 0; oq < 4; ++oq) {
            sv[oq] += __shfl_xor(sv[oq], masks[mi]);
            qv[oq] += __shfl_xor(qv[oq], masks[mi]);
        }
    }
    if ((lane & 55) == 0) {  // lanes 0, 8
        int gb = (lane >> 3) & 1;
#pragma unroll
        for (int oq = 0; oq < 4; ++oq) {
            atomicAdd(&sred[oq * 2 + gb][0], sv[oq]);
            atomicAdd(&sred[oq * 2 + gb][1], qv[oq]);
        }
    }
    // store: D row = quad*4 + r (px), col = o
    const int pxb = x0 + wid * 16 + quad * 4;
    float* Yb = Y + ((size_t)(b * 32 + y) * 1024 + pxb) * 64;
#pragma unroll
    for (int oq = 0; oq < 4; ++oq) {
        const float av[4] = {acc[oq].x, acc[oq].y, acc[oq].z, acc[oq].w};
#pragma unroll
        for (int r = 0; r < 4; ++r) Yb[(size_t)r * 64 + oq * 16 + m] = av[r];
    }
    __syncthreads();
    if (tid < 16)
        atomicAdd(&stats2[(b * 8 + (tid >> 1)) * 2 + (tid & 1)], sred[tid >> 1][tid & 1]);
}

// ---------------- fused GN2-apply + GELU + rh3 head ----------------
__global__ __launch_bounds__(256) void rh3_kernel(
    const float* __restrict__ H2, const float* __restrict__ stats,
    const float* __restrict__ gamma, const float* __restrict__ beta, float inv_cnt,
    const float* __restrict__ w3, const float* __restrict__ b3,
    const float2* __restrict__ azsc,
    float2* __restrict__ refxy, float2* __restrict__ sigf) {
    const int tid = threadIdx.x;
    const int lane = tid & 15;
    const int m = blockIdx.x * 16 + (tid >> 4);
    const int b = m >> 15;
    const int c = lane * 4;
    const int g = c >> 3;
    float mean = stats[(b * 8 + g) * 2 + 0] * inv_cnt;
    float var = stats[(b * 8 + g) * 2 + 1] * inv_cnt - mean * mean;
    float rs = 1.0f / sqrtf(var + 1e-5f);
    float4 v = *(const float4*)(H2 + (size_t)m * 64 + c);
    float hv[4];
    hv[0] = gelu_f((v.x - mean) * rs * gamma[c + 0] + beta[c + 0]);
    hv[1] = gelu_f((v.y - mean) * rs * gamma[c + 1] + beta[c + 1]);
    hv[2] = gelu_f((v.z - mean) * rs * gamma[c + 2] + beta[c + 2]);
    hv[3] = gelu_f((v.w - mean) * rs * gamma[c + 3] + beta[c + 3]);
    float d0 = 0.f, d1 = 0.f;
#pragma unroll
    for (int k = 0; k < 4; ++k) {
        d0 += hv[k] * w3[(c + k) * 2 + 0];
        d1 += hv[k] * w3[(c + k) * 2 + 1];
    }
#pragma unroll
    for (int s = 1; s < 16; s <<= 1) {
        d0 += __shfl_xor(d0, s, 16);
        d1 += __shfl_xor(d1, s, 16);
    }
    if (lane == 0) {
        float mu = fminf(fmaxf(d0 + b3[0], 0.f), 55.f);
        float ls = fminf(fmaxf(d1 + b3[1], -5.f), 3.f);
        float sg = expf(ls);
        float2 sc = azsc[m & 1023];
        float rx = fminf(fmaxf(mu * sc.y * 0.01f + 0.5f, 0.f), 1.f);
        float ry = fminf(fmaxf(mu * sc.x * 0.01f + 0.5f, 0.f), 1.f);
        refxy[m] = make_float2(rx, ry);
        sigf[m] = make_float2(ls, 1.f / (sg + 1e-6f));
    }
}

// ---------------- MSDA bilinear sampling ----------------
__device__ __forceinline__ float samp_v(const float* __restrict__ Vb, int x, int y) {
    bool valid = ((unsigned)x < 200u) && ((unsigned)y < 200u);
    int xc = min(max(x, 0), 199);
    int yc = min(max(y, 0), 199);
    float v = Vb[((size_t)yc * 200 + xc) * 128];
    return valid ? v : 0.f;
}

__global__ __launch_bounds__(256) void msda_kernel(
    const float* __restrict__ V, const float2* __restrict__ refxy,
    const float* __restrict__ offs, const float* __restrict__ aw,
    float* __restrict__ out) {
    const int tid = threadIdx.x;
    const int lane = tid & 15;
    const int grp = tid >> 4;
    const int m = blockIdx.x * 2 + (grp >> 3);
    const int head = grp & 7;
    const int b = m >> 15;
    float2 r = refxy[m];
    const float* lg = aw + (size_t)m * 48 + head * 6;
    float l[6];
#pragma unroll
    for (int p = 0; p < 6; ++p) l[p] = lg[p];
    float mx = l[0];
#pragma unroll
    for (int p = 1; p < 6; ++p) mx = fmaxf(mx, l[p]);
    float s = 0.f;
#pragma unroll
    for (int p = 0; p < 6; ++p) { l[p] = expf(l[p] - mx); s += l[p]; }
    float inv = 1.f / s;
    const float* of = offs + (size_t)m * 96 + head * 12;
    const float* Vb = V + (size_t)b * 40000 * 128 + head * 16 + lane;
    float acc = 0.f;
#pragma unroll
    for (int p = 0; p < 6; ++p) {
        float px = r.x * 200.f + of[p * 2 + 0] - 0.5f;
        float py = r.y * 200.f + of[p * 2 + 1] - 0.5f;
        float fx = floorf(px), fy = floorf(py);
        int x0 = (int)fx, y0 = (int)fy;
        float wx = px - fx, wy = py - fy;
        float v00 = samp_v(Vb, x0, y0);
        float v10 = samp_v(Vb, x0 + 1, y0);
        float v01 = samp_v(Vb, x0, y0 + 1);
        float v11 = samp_v(Vb, x0 + 1, y0 + 1);
        float bil = v00 * (1.f - wx) * (1.f - wy) + v10 * wx * (1.f - wy) +
                    v01 * (1.f - wx) * wy + v11 * wx * wy;
        acc += l[p] * inv * bil;
    }
    out[(size_t)m * 128 + head * 16 + lane] = acc;
}

// ---------------- launch ----------------
extern "C" void kernel_launch(void* const* d_in, const int* in_sizes, int n_in,
                              void* d_out, int out_size, void* d_ws, size_t ws_size,
                              hipStream_t stream) {
    const float* x_rv = (const float*)d_in[0];
    const float* bev = (const float*)d_in[1];
    const float* pq_w = (const float*)d_in[2];
    const float* pq_b = (const float*)d_in[3];
    const float* pv_w = (const float*)d_in[4];
    const float* pv_b = (const float*)d_in[5];
    const float* po_w = (const float*)d_in[6];
    const float* po_b = (const float*)d_in[7];
    const float* qs_w1 = (const float*)d_in[8];
    const float* qs_b1 = (const float*)d_in[9];
    const float* qs_w2 = (const float*)d_in[10];
    const float* qs_b2 = (const float*)d_in[11];
    const float* rh_w1 = (const float*)d_in[12];
    const float* rh_b1 = (const float*)d_in[13];
    const float* rh_g1 = (const float*)d_in[14];
    const float* rh_be1 = (const float*)d_in[15];
    const float* rh_w2 = (const float*)d_in[16];
    const float* rh_g2 = (const float*)d_in[17];
    const float* rh_be2 = (const float*)d_in[18];
    const float* rh_w3 = (const float*)d_in[19];
    const float* rh_b3 = (const float*)d_in[20];
    const float* so_w = (const float*)d_in[21];
    const float* so_b = (const float*)d_in[22];
    const float* aw_w = (const float*)d_in[23];
    const float* aw_b = (const float*)d_in[24];
    const float* vp_w = (const float*)d_in[25];
    const float* vp_b = (const float*)d_in[26];
    const float* op_w = (const float*)d_in[27];
    const float* op_b = (const float*)d_in[28];

    const int M = 65536;

    float* ws = (float*)d_ws;
    float* azsc = ws;    ws += 2048;
    float* pvvp_w = ws;  ws += 256 * 128;
    float* pvvp_b = ws;  ws += 128;
    float* oppo_w = ws;  ws += 128 * 128;
    float* oppo_b = ws;  ws += 128;
    float* pqqs_w = ws;  ws += 64 * 128;
    float* pqqs_b = ws;  ws += 128;
    float* qsso_w = ws;  ws += 128 * 96;
    float* qsso_b = ws;  ws += 128;
    float* qsaw_w = ws;  ws += 128 * 48;
    float* qsaw_b = ws;  ws += 64;
    float* stats = ws;   ws += 64;   // [0:32) GN1, [32:64) GN2
    unsigned short* wtb = (unsigned short*)ws;  ws += 36864;   // 73728 bf16
    unsigned short* h1b = (unsigned short*)ws;  ws += (size_t)M * 64;  // M*128 bf16
    float* Vv = ws;      ws += (size_t)80000 * 128;
    float* h1 = ws;      ws += (size_t)M * 128;
    float* h2 = ws;      ws += (size_t)M * 64;
    float* q1 = ws;      ws += (size_t)M * 128;
    float* refxy = ws;   ws += (size_t)M * 2;
    float* sigf = ws;    ws += (size_t)M * 2;
    size_t need_bytes = (size_t)(ws - (float*)d_ws) * sizeof(float);
    if (ws_size < need_bytes) return;
    float* offs = h1;   // h1 (raw rh1) dead after gn1_bf16
    float* attw = h2;   // h2 dead after rh3
    float* mo = q1;     // q1 dead after offs/attw GEMMs

    float2* azsc2 = (float2*)azsc;
    float2* refxy2 = (float2*)refxy;
    float2* sigf2 = (float2*)sigf;

    prep_weights<<<1293, 128, 0, stream>>>(
        pv_w, pv_b, vp_w, vp_b, op_w, op_b, po_w, po_b, pq_w, pq_b,
        qs_w1, qs_b1, qs_w2, qs_b2, so_w, so_b, aw_w, aw_b, rh_w2,
        pvvp_w, pvvp_b, oppo_w, oppo_b, pqqs_w, pqqs_b,
        qsso_w, qsso_b, qsaw_w, qsaw_b, wtb, azsc2);
    hipMemsetAsync(stats, 0, 64 * sizeof(float), stream);

    // h1 = raw rh1 (x_rv(+az) @ rh_w1 + b); fused GN1 stats
    gemm_v3<128, true><<<M / 128, 256, 0, stream>>>(
        x_rv, 64, rh_w1, rh_b1, h1, 64, azsc2, nullptr, rh_w1 + 64 * 128, 1, 0, stats);

    // value = bev^T @ (pv_w@vp_w) + fused bias
    value_gemm<<<dim3(313, 2), 256, 0, stream>>>(bev, pvvp_w, pvvp_b, Vv);

    // GN1 apply + gelu -> bf16
    gn1_bf16<<<8192, 256, 0, stream>>>(h1, stats, rh_g1, rh_be1, h1b);

    // conv via bf16 MFMA; GN2 stats in epilogue
    conv3x3_mfma<<<dim3(16, 32, 2), 256, 0, stream>>>(h1b, wtb, h2, stats + 32);

    // fused GN2-apply + gelu + rh3 head
    rh3_kernel<<<4096, 256, 0, stream>>>(h2, stats + 32, rh_g2, rh_be2, 1.0f / 262144.0f,
                                         rh_w3, rh_b3, azsc2, refxy2, sigf2);

    // q1 = gelu(x_rv @ (pq_w@qs_w1a) + sigf extras + fused bias)
    gemm_v3<128, false><<<M / 128, 256, 0, stream>>>(
        x_rv, 64, pqqs_w, pqqs_b, q1, 64, nullptr, sigf, qs_w1 + 128 * 128, 2, 1, nullptr);

    // offs = q1 @ (qs_w2@so_w) + folded bias
    gemm_v3<96, false><<<M / 128, 192, 0, stream>>>(
        q1, 128, qsso_w, qsso_b, offs, 128, nullptr, nullptr, nullptr, 0, 0, nullptr);

    // attw logits = q1 @ (qs_w2@aw_w) + folded bias
    gemm_rn<128, 48, 192><<<M / 128, 192, 0, stream>>>(
        q1, 128, qsaw_w, 48, qsaw_b, attw, 48, 128);

    // MSDA sampling (into q1)
    msda_kernel<<<M / 2, 256, 0, stream>>>(Vv, refxy2, offs, attw, mo);

    // y = mo @ (op_w@po_w) + fused bias -> d_out
    gemm_v3<128, false><<<M / 128, 256, 0, stream>>>(
        mo, 128, oppo_w, oppo_b, (float*)d_out, 128, nullptr, nullptr, nullptr, 0, 0, nullptr);
}